// Round 12
// baseline (1526.176 us; speedup 1.0000x reference)
//
#include <hip/hip_runtime.h>

#define DIM 2560
#define T_TOK 2048
#define NHEADS 20
#define HD 128
#define HID_E 6912
#define SHID_E 3584
#define MPAD 5120  // concat rows, segments padded to 256 (max 4096+4*255 <= 5120)

typedef _Float16 f16x8 __attribute__((ext_vector_type(8)));
typedef float f32x4 __attribute__((ext_vector_type(4)));
typedef unsigned short u16x8 __attribute__((ext_vector_type(8)));

#define MFMA16(a, b, c) __builtin_amdgcn_mfma_f32_16x16x32_f16((a), (b), (c), 0, 0, 0)

__device__ inline unsigned short f2h(float f) {
  return __builtin_bit_cast(unsigned short, (_Float16)f);
}
__device__ inline float h2f(unsigned short u) {
  return (float)__builtin_bit_cast(_Float16, u);
}
__device__ inline float wave_sum(float v) {
#pragma unroll
  for (int off = 32; off > 0; off >>= 1) v += __shfl_down(v, off, 64);
  return v;
}
// async global->LDS, 16B per lane; LDS dest = wave-uniform base + lane*16
__device__ inline void gld16(const void* g, void* l) {
  __builtin_amdgcn_global_load_lds((const __attribute__((address_space(1))) void*)g,
                                   (__attribute__((address_space(3))) void*)l, 16, 0, 0);
}

// ---------------- tiny kernels ----------------

__global__ __launch_bounds__(256) void silu_k(const float* __restrict__ t,
                                              float* __restrict__ ss) {
  int i = blockIdx.x * 256 + threadIdx.x;
  if (i < DIM) {
    float v = t[i];
    ss[i] = v / (1.f + expf(-v));
  }
}

// fused f32->fp16 conversion over 4 segments (n in groups of 8)
__global__ __launch_bounds__(256) void cvt_all4(
    const float* __restrict__ s0, unsigned short* __restrict__ d0, long n0,
    const float* __restrict__ s1, unsigned short* __restrict__ d1, long n1,
    const float* __restrict__ s2, unsigned short* __restrict__ d2, long n2,
    const float* __restrict__ s3, unsigned short* __restrict__ d3, long n3) {
  const long stride = (long)gridDim.x * 256;
  const long t01 = n0 + n1, t012 = t01 + n2, tot = t012 + n3;
  for (long i = (long)blockIdx.x * 256 + threadIdx.x; i < tot; i += stride) {
    const float* s;
    unsigned short* d;
    long j;
    if (i < n0) { s = s0; d = d0; j = i; }
    else if (i < t01) { s = s1; d = d1; j = i - n0; }
    else if (i < t012) { s = s2; d = d2; j = i - t01; }
    else { s = s3; d = d3; j = i - t012; }
    float4 a = *(const float4*)(s + j * 8);
    float4 b = *(const float4*)(s + j * 8 + 4);
    u16x8 u;
    u[0] = f2h(a.x); u[1] = f2h(a.y); u[2] = f2h(a.z); u[3] = f2h(a.w);
    u[4] = f2h(b.x); u[5] = f2h(b.y); u[6] = f2h(b.z); u[7] = f2h(b.w);
    *(u16x8*)&d[j * 8] = u;
  }
}

// fused w1/w3 interleave for all 4 experts + shared.
// row j of output group: (j&31)<16 ? w1[(j>>5)*16+(j&15)] : w3[(j>>5)*16+(j&15)]
__global__ __launch_bounds__(256) void cvt_pair_all(
    const float* __restrict__ ew1, const float* __restrict__ ew3,
    const float* __restrict__ sw1, const float* __restrict__ sw3,
    unsigned short* __restrict__ ewA, unsigned short* __restrict__ swA) {
  const int j = blockIdx.x;
  const float *w1, *w3;
  unsigned short* dst;
  int row;
  if (j < 4 * 2 * HID_E) {
    const int e = j / (2 * HID_E);
    row = j - e * 2 * HID_E;
    w1 = ew1 + (size_t)e * HID_E * DIM;
    w3 = ew3 + (size_t)e * HID_E * DIM;
    dst = ewA + (size_t)e * 2 * HID_E * DIM + (size_t)row * DIM;
  } else {
    row = j - 4 * 2 * HID_E;
    w1 = sw1;
    w3 = sw3;
    dst = swA + (size_t)row * DIM;
  }
  const int g = row >> 5, r = row & 31;
  const float* src = (r < 16) ? (w1 + (size_t)(g * 16 + r) * DIM)
                              : (w3 + (size_t)(g * 16 + (r & 15)) * DIM);
  for (int i = threadIdx.x; i < 320; i += 256) {
    float4 a = *(const float4*)(src + i * 8);
    float4 b = *(const float4*)(src + i * 8 + 4);
    u16x8 u;
    u[0] = f2h(a.x); u[1] = f2h(a.y); u[2] = f2h(a.z); u[3] = f2h(a.w);
    u[4] = f2h(b.x); u[5] = f2h(b.y); u[6] = f2h(b.z); u[7] = f2h(b.w);
    *(u16x8*)&dst[i * 8] = u;
  }
}

// mod[j] = dot(silu(temb), adaln_w[j]) + adaln_b[j]; one wave per output
__global__ __launch_bounds__(256) void adaln_gemv(const float* __restrict__ ss,
                                                  const float* __restrict__ W,
                                                  const float* __restrict__ bias,
                                                  float* __restrict__ mod) {
  const int lane = threadIdx.x & 63;
  const int j = blockIdx.x * 4 + (threadIdx.x >> 6);
  const float* wr = W + (size_t)j * DIM;
  float p = 0.f;
  for (int i = lane; i < 640; i += 64) {
    float4 w = *(const float4*)(wr + i * 4);
    float4 x = *(const float4*)(ss + i * 4);
    p += w.x * x.x + w.y * x.y + w.z * x.z + w.w * x.w;
  }
  p = wave_sum(p);
  if (lane == 0) mod[j] = p + bias[j];
}

// LN (no affine) then *(1+scale)+shift, write fp16. One block per row.
__global__ __launch_bounds__(256) void ln_mod(const float* __restrict__ x,
                                              const float* __restrict__ shift,
                                              const float* __restrict__ scale,
                                              unsigned short* __restrict__ outp) {
  __shared__ float rbuf[8];
  const int t = blockIdx.x, tid = threadIdx.x, lane = tid & 63, wid = tid >> 6;
  const float* xr = x + (size_t)t * DIM;
  float s = 0.f, sq = 0.f;
  for (int i = tid; i < 640; i += 256) {
    float4 v = *(const float4*)(xr + i * 4);
    s += v.x + v.y + v.z + v.w;
    sq += v.x * v.x + v.y * v.y + v.z * v.z + v.w * v.w;
  }
  s = wave_sum(s);
  sq = wave_sum(sq);
  if (lane == 0) {
    rbuf[wid] = s;
    rbuf[4 + wid] = sq;
  }
  __syncthreads();
  float S = rbuf[0] + rbuf[1] + rbuf[2] + rbuf[3];
  float SQ = rbuf[4] + rbuf[5] + rbuf[6] + rbuf[7];
  float mean = S * (1.f / DIM);
  float rs = rsqrtf(SQ * (1.f / DIM) - mean * mean + 1e-6f);
  for (int i = tid; i < 640; i += 256) {
    float4 v = *(const float4*)(xr + i * 4);
    float4 sc4 = *(const float4*)(scale + i * 4);
    float4 sh4 = *(const float4*)(shift + i * 4);
    ushort4 u;
    u.x = f2h((v.x - mean) * rs * (1.f + sc4.x) + sh4.x);
    u.y = f2h((v.y - mean) * rs * (1.f + sc4.y) + sh4.y);
    u.z = f2h((v.z - mean) * rs * (1.f + sc4.z) + sh4.z);
    u.w = f2h((v.w - mean) * rs * (1.f + sc4.w) + sh4.w);
    *(ushort4*)&outp[(size_t)t * DIM + i * 4] = u;
  }
}

// RMSNorm(q),(k) over full 2560 + weight + RoPE -> qh (scaled by 1/sqrt(128)), kh
__global__ __launch_bounds__(256) void rmsrope(const unsigned short* __restrict__ qkv,
                                               const float* __restrict__ qn,
                                               const float* __restrict__ kn,
                                               const float* __restrict__ rope,
                                               unsigned short* __restrict__ qh,
                                               unsigned short* __restrict__ kh) {
  __shared__ float rbuf[8];
  const int t = blockIdx.x, tid = threadIdx.x, lane = tid & 63, wid = tid >> 6;
  const unsigned short* row = qkv + (size_t)t * 7680;
  float sq = 0.f, sk = 0.f;
  for (int i = tid; i < 320; i += 256) {
    f16x8 qv = *(const f16x8*)(row + i * 8);
    f16x8 kv = *(const f16x8*)(row + DIM + i * 8);
#pragma unroll
    for (int j = 0; j < 8; ++j) {
      float q = (float)qv[j], k = (float)kv[j];
      sq += q * q;
      sk += k * k;
    }
  }
  sq = wave_sum(sq);
  sk = wave_sum(sk);
  if (lane == 0) {
    rbuf[wid] = sq;
    rbuf[4 + wid] = sk;
  }
  __syncthreads();
  float SQ = rbuf[0] + rbuf[1] + rbuf[2] + rbuf[3];
  float SK = rbuf[4] + rbuf[5] + rbuf[6] + rbuf[7];
  float rq = rsqrtf(SQ * (1.f / DIM) + 1e-6f) * 0.08838834764831845f;
  float rk = rsqrtf(SK * (1.f / DIM) + 1e-6f);
  for (int pp = tid; pp < 1280; pp += 256) {
    int c = pp * 2;
    float qe = h2f(row[c]) * rq * qn[c], qo = h2f(row[c + 1]) * rq * qn[c + 1];
    float ke = h2f(row[DIM + c]) * rk * kn[c], ko = h2f(row[DIM + c + 1]) * rk * kn[c + 1];
    float4 rr = *(const float4*)(rope + (size_t)t * 256 + (pp & 63) * 4);
    unsigned qp = (unsigned)f2h(rr.x * qe + rr.y * qo) |
                  ((unsigned)f2h(rr.z * qe + rr.w * qo) << 16);
    unsigned kp = (unsigned)f2h(rr.x * ke + rr.y * ko) |
                  ((unsigned)f2h(rr.z * ke + rr.w * ko) << 16);
    *(unsigned*)&qh[(size_t)t * DIM + c] = qp;
    *(unsigned*)&kh[(size_t)t * DIM + c] = kp;
  }
}

// V part of qkv (fp16 [2048][7680] at col 5120) -> vt fp16 [2560][2048]
__global__ void transpose_v(const unsigned short* __restrict__ in,
                            unsigned short* __restrict__ outp) {
  __shared__ unsigned short tile[32][33];
  const int bx = blockIdx.x * 32;  // channel
  const int by = blockIdx.y * 32;  // token
  const int tx = threadIdx.x, ty = threadIdx.y;
  for (int j = ty; j < 32; j += 8)
    tile[j][tx] = in[(size_t)(by + j) * 7680 + 5120 + bx + tx];
  __syncthreads();
  for (int j = ty; j < 32; j += 8)
    outp[(size_t)(bx + j) * T_TOK + by + tx] = tile[tx][j];
}

// ---------------- MFMA flash attention: TWO 64-q tiles per block (shared K/V) ----------
// grid (16, 20). Set A's Q in registers; set B's Q in LDS (re-read per tile).
__global__ __launch_bounds__(256) void fattn(const unsigned short* __restrict__ qh,
                                             const unsigned short* __restrict__ kh,
                                             const unsigned short* __restrict__ vt,
                                             unsigned short* __restrict__ obuf) {
  __shared__ unsigned short sK[64 * 128];   // [k][d], slot = c ^ (r&15)
  __shared__ unsigned short sQb[64 * 128];  // set-B Q tile, same swizzle
  __shared__ unsigned short sV[128 * 64];   // [d][k], slot = c ^ (r&7)
  __shared__ unsigned short sP[64 * 64];    // [q][k], slot = c ^ (r&7)
  __shared__ float sRedM[4][64];
  __shared__ float sRedL[4][64];
  __shared__ float sM[64];
  __shared__ float sL[64];
  const int tid = threadIdx.x, lane = tid & 63, wv = tid >> 6;
  const int g = lane >> 4, fr = lane & 15;
  const int h = blockIdx.y;
  const int q0 = blockIdx.x * 128;

  // ---- stage Qa into sK, Qb into sQb ----
  {
    const int r = tid >> 2, qt = tid & 3;
    const int cb = qt * 4, rs = r & 15;
    {
      const unsigned short* gp = qh + (size_t)(q0 + r) * DIM + h * HD + qt * 32;
      uint4 v0 = ((const uint4*)gp)[0];
      uint4 v1 = ((const uint4*)gp)[1];
      uint4 v2 = ((const uint4*)gp)[2];
      uint4 v3 = ((const uint4*)gp)[3];
      unsigned short* dst = &sK[r * 128];
      *(uint4*)&dst[((cb + 0) ^ rs) * 8] = v0;
      *(uint4*)&dst[((cb + 1) ^ rs) * 8] = v1;
      *(uint4*)&dst[((cb + 2) ^ rs) * 8] = v2;
      *(uint4*)&dst[((cb + 3) ^ rs) * 8] = v3;
    }
    {
      const unsigned short* gp = qh + (size_t)(q0 + 64 + r) * DIM + h * HD + qt * 32;
      uint4 v0 = ((const uint4*)gp)[0];
      uint4 v1 = ((const uint4*)gp)[1];
      uint4 v2 = ((const uint4*)gp)[2];
      uint4 v3 = ((const uint4*)gp)[3];
      unsigned short* dst = &sQb[r * 128];
      *(uint4*)&dst[((cb + 0) ^ rs) * 8] = v0;
      *(uint4*)&dst[((cb + 1) ^ rs) * 8] = v1;
      *(uint4*)&dst[((cb + 2) ^ rs) * 8] = v2;
      *(uint4*)&dst[((cb + 3) ^ rs) * 8] = v3;
    }
  }
  __syncthreads();
  f16x8 qfragA[4][4];
#pragma unroll
  for (int ni = 0; ni < 4; ++ni) {
#pragma unroll
    for (int kt = 0; kt < 4; ++kt) {
      int r = ni * 16 + fr;
      qfragA[ni][kt] = *(const f16x8*)&sK[r * 128 + (((kt * 4 + g) ^ (r & 15)) << 3)];
    }
  }
  __syncthreads();

  f32x4 acco[2][4][2];
  f32x4 mprev[2][4];
  float mrun[2][4], lrun[2][4];
#pragma unroll
  for (int s = 0; s < 2; ++s) {
#pragma unroll
    for (int i = 0; i < 4; ++i) {
      acco[s][i][0] = (f32x4)0.f;
      acco[s][i][1] = (f32x4)0.f;
      mprev[s][i] = (f32x4)(-1e30f);
      mrun[s][i] = -1e30f;
      lrun[s][i] = 0.f;
    }
  }

  for (int kt0 = 0; kt0 < T_TOK; kt0 += 64) {
    {  // stage K tile [64][128] + V tile [128][64]
      const int r = tid >> 2, qt = tid & 3;
      const unsigned short* gp = kh + (size_t)(kt0 + r) * DIM + h * HD + qt * 32;
      uint4 v0 = ((const uint4*)gp)[0];
      uint4 v1 = ((const uint4*)gp)[1];
      uint4 v2 = ((const uint4*)gp)[2];
      uint4 v3 = ((const uint4*)gp)[3];
      unsigned short* dst = &sK[r * 128];
      const int cb = qt * 4, rs = r & 15;
      *(uint4*)&dst[((cb + 0) ^ rs) * 8] = v0;
      *(uint4*)&dst[((cb + 1) ^ rs) * 8] = v1;
      *(uint4*)&dst[((cb + 2) ^ rs) * 8] = v2;
      *(uint4*)&dst[((cb + 3) ^ rs) * 8] = v3;
      const int rv = tid >> 1, hf = tid & 1;
      const unsigned short* gv = vt + (size_t)(h * HD + rv) * T_TOK + kt0 + hf * 32;
      uint4 w0 = ((const uint4*)gv)[0];
      uint4 w1 = ((const uint4*)gv)[1];
      uint4 w2 = ((const uint4*)gv)[2];
      uint4 w3 = ((const uint4*)gv)[3];
      unsigned short* dv = &sV[rv * 64];
      const int cv = hf * 4, rvs = rv & 7;
      *(uint4*)&dv[((cv + 0) ^ rvs) * 8] = w0;
      *(uint4*)&dv[((cv + 1) ^ rvs) * 8] = w1;
      *(uint4*)&dv[((cv + 2) ^ rvs) * 8] = w2;
      *(uint4*)&dv[((cv + 3) ^ rvs) * 8] = w3;
    }
    __syncthreads();  // B0: K,V ready (also guards prev tile's set-B PV reads)

#pragma unroll
    for (int s = 0; s < 2; ++s) {
      // ---- S^T = K · Q^T ----
      f32x4 accs[4] = {(f32x4)0.f, (f32x4)0.f, (f32x4)0.f, (f32x4)0.f};
#pragma unroll
      for (int kt = 0; kt < 4; ++kt) {
        int r = wv * 16 + fr;
        f16x8 ak = *(const f16x8*)&sK[r * 128 + (((kt * 4 + g) ^ (r & 15)) << 3)];
#pragma unroll
        for (int ni = 0; ni < 4; ++ni) {
          f16x8 q;
          if (s == 0) {
            q = qfragA[ni][kt];
          } else {
            int rq = ni * 16 + fr;
            q = *(const f16x8*)&sQb[rq * 128 + (((kt * 4 + g) ^ (rq & 15)) << 3)];
          }
          accs[ni] = MFMA16(ak, q, accs[ni]);
        }
      }

      // ---- softmax ----
      float pm[4];
#pragma unroll
      for (int ni = 0; ni < 4; ++ni) {
        float m = fmaxf(fmaxf(accs[ni][0], accs[ni][1]), fmaxf(accs[ni][2], accs[ni][3]));
        m = fmaxf(m, __shfl_xor(m, 16));
        m = fmaxf(m, __shfl_xor(m, 32));
        pm[ni] = m;
      }
      if (g == 0) {
#pragma unroll
        for (int ni = 0; ni < 4; ++ni) sRedM[wv][ni * 16 + fr] = pm[ni];
      }
      __syncthreads();  // B1(s)
      float mnew[4];
#pragma unroll
      for (int ni = 0; ni < 4; ++ni) {
        int q = ni * 16 + fr;
        float mt = fmaxf(fmaxf(sRedM[0][q], sRedM[1][q]), fmaxf(sRedM[2][q], sRedM[3][q]));
        mnew[ni] = fmaxf(mrun[s][ni], mt);
      }
      float lsum[4];
#pragma unroll
      for (int ni = 0; ni < 4; ++ni) {
        float l0 = 0.f;
#pragma unroll
        for (int i = 0; i < 4; ++i) {
          float p = __expf(accs[ni][i] - mnew[ni]);
          accs[ni][i] = p;
          l0 += p;
        }
        l0 += __shfl_xor(l0, 16);
        l0 += __shfl_xor(l0, 32);
        lsum[ni] = l0;
      }
      if (g == 0) {
#pragma unroll
        for (int ni = 0; ni < 4; ++ni) sRedL[wv][ni * 16 + fr] = lsum[ni];
        if (wv == 0) {
#pragma unroll
          for (int ni = 0; ni < 4; ++ni) sM[ni * 16 + fr] = mnew[ni];
        }
      }
#pragma unroll
      for (int ni = 0; ni < 4; ++ni) {
        int q = ni * 16 + fr;
        unsigned p01 = (unsigned)f2h(accs[ni][0]) | ((unsigned)f2h(accs[ni][1]) << 16);
        unsigned p23 = (unsigned)f2h(accs[ni][2]) | ((unsigned)f2h(accs[ni][3]) << 16);
        uint2 pk;
        pk.x = p01;
        pk.y = p23;
        *(uint2*)&sP[q * 64 + ((((wv << 1) | (g >> 1)) ^ (q & 7)) << 3) + ((g & 1) << 2)] = pk;
      }
      __syncthreads();  // B2(s)
#pragma unroll
      for (int ni = 0; ni < 4; ++ni) {
        int q = ni * 16 + fr;
        float lt = sRedL[0][q] + sRedL[1][q] + sRedL[2][q] + sRedL[3][q];
        lrun[s][ni] = lrun[s][ni] * __expf(mrun[s][ni] - mnew[ni]) + lt;
        mrun[s][ni] = mnew[ni];
      }

      // ---- PV ----
#pragma unroll
      for (int mi = 0; mi < 4; ++mi) {
        f32x4 mn = *(const f32x4*)&sM[mi * 16 + g * 4];
        f32x4 sc;
#pragma unroll
        for (int i = 0; i < 4; ++i) sc[i] = __expf(mprev[s][mi][i] - mn[i]);
        acco[s][mi][0] *= sc;
        acco[s][mi][1] *= sc;
        mprev[s][mi] = mn;
      }
#pragma unroll
      for (int ktp = 0; ktp < 2; ++ktp) {
        f16x8 bv[2];
#pragma unroll
        for (int nd = 0; nd < 2; ++nd) {
          int r = wv * 32 + nd * 16 + fr;
          bv[nd] = *(const f16x8*)&sV[r * 64 + (((ktp * 4 + g) ^ (r & 7)) << 3)];
        }
#pragma unroll
        for (int mi = 0; mi < 4; ++mi) {
          int r = mi * 16 + fr;
          f16x8 ap = *(const f16x8*)&sP[r * 64 + (((ktp * 4 + g) ^ (r & 7)) << 3)];
          acco[s][mi][0] = MFMA16(ap, bv[0], acco[s][mi][0]);
          acco[s][mi][1] = MFMA16(ap, bv[1], acco[s][mi][1]);
        }
      }
      __syncthreads();  // B3(s): frees sP/sRedM/sM for next set (or next tile's staging)
    }
  }

  // ---- epilogue (per set, barrier-separated) ----
#pragma unroll
  for (int s = 0; s < 2; ++s) {
    if (wv == 0 && g == 0) {
#pragma unroll
      for (int ni = 0; ni < 4; ++ni) sL[ni * 16 + fr] = 1.f / lrun[s][ni];
    }
    __syncthreads();
#pragma unroll
    for (int mi = 0; mi < 4; ++mi) {
      f32x4 li = *(const f32x4*)&sL[mi * 16 + g * 4];
#pragma unroll
      for (int nd = 0; nd < 2; ++nd) {
#pragma unroll
        for (int i = 0; i < 4; ++i) {
          float o = acco[s][mi][nd][i] * li[i];
          obuf[(size_t)(q0 + s * 64 + mi * 16 + g * 4 + i) * DIM + h * HD + wv * 32 +
               nd * 16 + fr] = f2h(o);
        }
      }
    }
    __syncthreads();
  }
}

// LN2 + modulate -> nh2 fp16, plus f32 routing (softmax over 4, top-2, unnormalized)
__global__ __launch_bounds__(256) void ln2_route(const float* __restrict__ x,
                                                 const float* __restrict__ shift,
                                                 const float* __restrict__ scale,
                                                 const float* __restrict__ gw,
                                                 unsigned short* __restrict__ nh2,
                                                 float* __restrict__ wd) {
  __shared__ float rbuf[8];
  __shared__ float gbuf[4][4];
  const int t = blockIdx.x, tid = threadIdx.x, lane = tid & 63, wid = tid >> 6;
  const float* xr = x + (size_t)t * DIM;
  float s = 0.f, sq = 0.f;
  for (int i = tid; i < 640; i += 256) {
    float4 v = *(const float4*)(xr + i * 4);
    s += v.x + v.y + v.z + v.w;
    sq += v.x * v.x + v.y * v.y + v.z * v.z + v.w * v.w;
  }
  s = wave_sum(s);
  sq = wave_sum(sq);
  if (lane == 0) {
    rbuf[wid] = s;
    rbuf[4 + wid] = sq;
  }
  __syncthreads();
  float S = rbuf[0] + rbuf[1] + rbuf[2] + rbuf[3];
  float SQ = rbuf[4] + rbuf[5] + rbuf[6] + rbuf[7];
  float mean = S * (1.f / DIM);
  float rs = rsqrtf(SQ * (1.f / DIM) - mean * mean + 1e-6f);
  float g0 = 0.f, g1 = 0.f, g2 = 0.f, g3 = 0.f;
  for (int i = tid; i < 640; i += 256) {
    float4 v = *(const float4*)(xr + i * 4);
    float4 sc4 = *(const float4*)(scale + i * 4);
    float4 sh4 = *(const float4*)(shift + i * 4);
    float y0 = (v.x - mean) * rs * (1.f + sc4.x) + sh4.x;
    float y1 = (v.y - mean) * rs * (1.f + sc4.y) + sh4.y;
    float y2 = (v.z - mean) * rs * (1.f + sc4.z) + sh4.z;
    float y3 = (v.w - mean) * rs * (1.f + sc4.w) + sh4.w;
    ushort4 u;
    u.x = f2h(y0); u.y = f2h(y1); u.z = f2h(y2); u.w = f2h(y3);
    *(ushort4*)&nh2[(size_t)t * DIM + i * 4] = u;
    float4 w0 = *(const float4*)(gw + i * 4);
    float4 w1 = *(const float4*)(gw + DIM + i * 4);
    float4 w2 = *(const float4*)(gw + 2 * DIM + i * 4);
    float4 w3 = *(const float4*)(gw + 3 * DIM + i * 4);
    g0 += y0 * w0.x + y1 * w0.y + y2 * w0.z + y3 * w0.w;
    g1 += y0 * w1.x + y1 * w1.y + y2 * w1.z + y3 * w1.w;
    g2 += y0 * w2.x + y1 * w2.y + y2 * w2.z + y3 * w2.w;
    g3 += y0 * w3.x + y1 * w3.y + y2 * w3.z + y3 * w3.w;
  }
  g0 = wave_sum(g0);
  g1 = wave_sum(g1);
  g2 = wave_sum(g2);
  g3 = wave_sum(g3);
  if (lane == 0) {
    gbuf[wid][0] = g0; gbuf[wid][1] = g1; gbuf[wid][2] = g2; gbuf[wid][3] = g3;
  }
  __syncthreads();
  if (tid == 0) {
    float l[4];
#pragma unroll
    for (int e = 0; e < 4; ++e) l[e] = gbuf[0][e] + gbuf[1][e] + gbuf[2][e] + gbuf[3][e];
    float mx = fmaxf(fmaxf(l[0], l[1]), fmaxf(l[2], l[3]));
    float ex[4], sum = 0.f;
#pragma unroll
    for (int e = 0; e < 4; ++e) { ex[e] = expf(l[e] - mx); sum += ex[e]; }
    float p[4];
#pragma unroll
    for (int e = 0; e < 4; ++e) p[e] = ex[e] / sum;
    int i1 = 0;
    for (int e = 1; e < 4; ++e)
      if (p[e] > p[i1]) i1 = e;
    int i2 = -1;
    for (int e = 0; e < 4; ++e) {
      if (e == i1) continue;
      if (i2 < 0 || p[e] > p[i2]) i2 = e;
    }
    float w[4] = {0.f, 0.f, 0.f, 0.f};
    w[i1] = p[i1];
    w[i2] = p[i2];
    *(float4*)&wd[(size_t)t * 4] = make_float4(w[0], w[1], w[2], w[3]);
  }
}

// Concatenated padded top-2 compaction. One block, 256 threads, 8 tokens each.
// Segments padded to 256 (for the 256-tile GEMM). idx pad rows point at token 0.
__global__ __launch_bounds__(256) void route_compact(const float* __restrict__ wd,
                                                     int* __restrict__ idx_all,
                                                     int* __restrict__ seg,
                                                     int* __restrict__ slotAB,
                                                     float* __restrict__ wAB) {
  __shared__ unsigned short c[256][4];
  __shared__ int offs[256][4];
  __shared__ int segs[5];
  const int t = threadIdx.x;
  for (int i = t; i < MPAD; i += 256) idx_all[i] = 0;
  unsigned char sel[8];
  float wv4[8][4];
  unsigned short lc[4] = {0, 0, 0, 0};
#pragma unroll
  for (int k = 0; k < 8; ++k) {
    int tok = t * 8 + k;
    float4 w = *(const float4*)&wd[(size_t)tok * 4];
    wv4[k][0] = w.x; wv4[k][1] = w.y; wv4[k][2] = w.z; wv4[k][3] = w.w;
    unsigned m = 0;
    if (w.x != 0.f) { m |= 1; lc[0]++; }
    if (w.y != 0.f) { m |= 2; lc[1]++; }
    if (w.z != 0.f) { m |= 4; lc[2]++; }
    if (w.w != 0.f) { m |= 8; lc[3]++; }
    sel[k] = (unsigned char)m;
  }
#pragma unroll
  for (int e = 0; e < 4; ++e) c[t][e] = lc[e];
  __syncthreads();
  if (t == 0) {
    int run[4] = {0, 0, 0, 0};
    for (int i = 0; i < 256; ++i) {
#pragma unroll
      for (int e = 0; e < 4; ++e) {
        offs[i][e] = run[e];
        run[e] += c[i][e];
      }
    }
    int s = 0;
    segs[0] = 0;
#pragma unroll
    for (int e = 0; e < 4; ++e) {
      s += (run[e] + 255) & ~255;
      segs[e + 1] = s;
    }
#pragma unroll
    for (int e = 0; e < 5; ++e) seg[e] = segs[e];
  }
  __syncthreads();
  int o[4];
#pragma unroll
  for (int e = 0; e < 4; ++e) o[e] = segs[e] + offs[t][e];
#pragma unroll
  for (int k = 0; k < 8; ++k) {
    int tok = t * 8 + k;
    unsigned m = sel[k];
    int sl[2] = {0, 0};
    float sw[2] = {0.f, 0.f};
    int ns = 0;
#pragma unroll
    for (int e = 0; e < 4; ++e) {
      if ((m >> e) & 1) {
        if (ns < 2) { sl[ns] = o[e]; sw[ns] = wv4[k][e]; }
        idx_all[o[e]++] = tok;
        ns++;
      }
    }
    if (ns == 1) { sl[1] = sl[0]; sw[1] = 0.f; }
    slotAB[tok * 2] = sl[0];
    slotAB[tok * 2 + 1] = sl[1];
    wAB[tok * 2] = sw[0];
    wAB[tok * 2 + 1] = sw[1];
  }
}

// ---------------- gemm128: kept for out-proj / final (epilogue-heavy) ----------------
// EPI: 1 f32 aux0[n]*(v+bias)+aux1 | 4 fp16(+bias) |
//      6 final: aux0[n]*(v + wA*yc[slA]+wB*yc[slB]) + aux1
template <int EPI, int MODE>
__global__ __launch_bounds__(256) void gemm128(
    const unsigned short* __restrict__ A, const unsigned short* __restrict__ B,
    const float* __restrict__ bias, void* __restrict__ Cv,
    const float* __restrict__ aux0, const float* __restrict__ aux1,
    const int* __restrict__ idx, const int* __restrict__ seg,
    const int* __restrict__ slotAB, const float* __restrict__ wAB,
    const unsigned short* __restrict__ yc, int M, int N, int K) {
  __shared__ unsigned short smem[16384];  // 2 bufs x (A 4096 + B 4096)
  const int tid = threadIdx.x;
  const int lane = tid & 63;
  const int wv = tid >> 6;
  const int nwg = gridDim.x;
  const int bid = blockIdx.x;
  const int swzb = (bid & 7) * (nwg >> 3) + (bid >> 3);
  const int gm = M >> 7;
  const int m0 = (swzb % gm) * 128, n0 = (swzb / gm) * 128;
  if (MODE != 0 && m0 >= seg[4]) return;

  const unsigned short* Bp = B;
  if constexpr (MODE != 0) {
    int e = 0;
#pragma unroll
    for (int i = 1; i < 4; ++i)
      if (m0 >= seg[i]) e = i;
    Bp = B + (size_t)e * N * K;
  }

  const int wm = (wv >> 1) * 64, wn = (wv & 1) * 64;
  const int fr = lane & 15, fc = lane >> 4;

  const int rl = lane >> 2, ch = lane & 3;
  const int R1 = wv * 16 + rl;
  const int R2 = 64 + R1;
  const int co1 = ((ch ^ ((R1 >> 1) & 3)) << 3);
  const int co2 = ((ch ^ ((R2 >> 1) & 3)) << 3);
  const size_t ar1 = (size_t)(m0 + R1) * K;
  const size_t ar2 = (size_t)(m0 + R2) * K;
  const unsigned short* gA1 = A + ar1 + co1;
  const unsigned short* gA2 = A + ar2 + co2;
  const unsigned short* gB1 = Bp + (size_t)(n0 + R1) * K + co1;
  const unsigned short* gB2 = Bp + (size_t)(n0 + R2) * K + co2;
  const int lA1 = (wv * 16) * 32, lA2 = (64 + wv * 16) * 32;

  f32x4 acc[4][4];
#pragma unroll
  for (int i = 0; i < 4; ++i) {
#pragma unroll
    for (int j = 0; j < 4; ++j) acc[i][j] = (f32x4)0.f;
  }

  auto STAGE = [&](int buf, int kt) {
    unsigned short* base = smem + buf * 8192;
    gld16(gA1 + kt, base + lA1);
    gld16(gA2 + kt, base + lA2);
    gld16(gB1 + kt, base + 4096 + lA1);
    gld16(gB2 + kt, base + 4096 + lA2);
  };
  auto COMPUTE = [&](int buf) {
    const unsigned short* sA = smem + buf * 8192;
    const unsigned short* sB = sA + 4096;
    f16x8 a[4], b[4];
#pragma unroll
    for (int mi = 0; mi < 4; ++mi) {
      int r = wm + mi * 16 + fr;
      a[mi] = *(const f16x8*)&sA[r * 32 + ((fc ^ ((r >> 1) & 3)) << 3)];
    }
#pragma unroll
    for (int ni = 0; ni < 4; ++ni) {
      int r = wn + ni * 16 + fr;
      b[ni] = *(const f16x8*)&sB[r * 32 + ((fc ^ ((r >> 1) & 3)) << 3)];
    }
#pragma unroll
    for (int mi = 0; mi < 4; ++mi) {
#pragma unroll
      for (int ni = 0; ni < 4; ++ni) acc[mi][ni] = MFMA16(a[mi], b[ni], acc[mi][ni]);
    }
  };

  const int nk = K >> 5;
  STAGE(0, 0);
  __syncthreads();
  int cur = 0;
  for (int t = 1; t < nk; ++t) {
    STAGE(cur ^ 1, t << 5);
    COMPUTE(cur);
    __syncthreads();
    cur ^= 1;
  }
  COMPUTE(cur);

#pragma unroll
  for (int mi = 0; mi < 4; ++mi) {
#pragma unroll
    for (int ni = 0; ni < 4; ++ni) {
      const int n = n0 + wn + ni * 16 + fr;
      const int mb = m0 + wm + mi * 16 + fc * 4;
#pragma unroll
      for (int i = 0; i < 4; ++i) {
        const int m = mb + i;
        float v = acc[mi][ni][i];
        const size_t cidx = (size_t)m * N + n;
        if constexpr (EPI == 1) {
          ((float*)Cv)[cidx] = aux0[n] * (v + bias[n]) + aux1[cidx];
        } else if constexpr (EPI == 4) {
          if (bias) v += bias[n];
          ((unsigned short*)Cv)[cidx] = f2h(v);
        } else if constexpr (EPI == 6) {
          const int sA_ = slotAB[m * 2], sB_ = slotAB[m * 2 + 1];
          const float wA_ = wAB[m * 2], wB_ = wAB[m * 2 + 1];
          float vm = wA_ * h2f(yc[(size_t)sA_ * N + n]) + wB_ * h2f(yc[(size_t)sB_ * N + n]);
          ((float*)Cv)[cidx] = aux0[n] * (v + vm) + aux1[cidx];
        }
      }
    }
  }
}

// ---------------- gemm256: 256x256 tile, 8 waves, BK=32, depth-2 counted pipeline ----------
// Per iter: vmcnt(4) + barrier; 12 ds_reads; issue tile t+2 loads; setprio(1) 32 MFMA.
// MODE: 0 dense | 1 gather: A rows = idx[m], B by 256-aligned seg | 2 direct A, B by seg.
// EPI: 4 fp16(+bias) | 5 fused swiglu -> fp16, Nh=N/2
template <int EPI, int MODE>
__global__ __launch_bounds__(512) void gemm256(
    const unsigned short* __restrict__ A, const unsigned short* __restrict__ B,
    const float* __restrict__ bias, void* __restrict__ Cv,
    const int* __restrict__ idx, const int* __restrict__ seg,
    int M, int N, int K) {
  __shared__ unsigned short smem[49152];  // 3 bufs x 16384 shorts (32KB each)
  const int tid = threadIdx.x;
  const int lane = tid & 63;
  const int wv = tid >> 6;           // 0..7
  const int wr = wv >> 2;            // 0..1 (m half)
  const int wc = wv & 3;             // 0..3 (n quarter)
  const int fr = lane & 15, fc = lane >> 4;

  const int nwg = gridDim.x;
  const int bid = blockIdx.x;
  const int swzb = (bid & 7) * (nwg >> 3) + (bid >> 3);
  const int gm = M >> 8;
  const int m0 = (swzb % gm) * 256, n0 = (swzb / gm) * 256;
  if (MODE != 0 && m0 >= seg[4]) return;

  const unsigned short* Bp = B;
  if constexpr (MODE != 0) {
    int e = 0;
#pragma unroll
    for (int i = 1; i < 4; ++i)
      if (m0 >= seg[i]) e = i;
    Bp = B + (size_t)e * N * K;
  }

  // staging: per K-tile 4 gld16/wave: A rows [wv*16,+16) of each 128-half, same for B.
  const int srow = (lane >> 2);            // 0..15 within 16-row group
  const int srcc = ((lane & 3) ^ ((lane >> 3) & 3)) << 3;  // pre-swizzled chunk (shorts)
  int mr0, mr1;
  if constexpr (MODE == 1) {
    mr0 = idx[m0 + wv * 16 + srow];
    mr1 = idx[m0 + 128 + wv * 16 + srow];
  } else {
    mr0 = m0 + wv * 16 + srow;
    mr1 = m0 + 128 + wv * 16 + srow;
  }
  const unsigned short* gA0 = A + (size_t)mr0 * K + srcc;
  const unsigned short* gA1 = A + (size_t)mr1 * K + srcc;
  const unsigned short* gB0 = Bp + (size_t)(n0 + wv * 16 + srow) * K + srcc;
  const unsigned short* gB1 = Bp + (size_t)(n0 + 128 + wv * 16 + srow) * K + srcc;
  const int lw = wv << 9;  // wv*16 rows * 32 shorts

  // fragment read offsets (shorts); frag stride = 16 rows * 32 = 512
  const int sw = (fr >> 1) & 3;
  const int fo = ((fc ^ sw) << 3);
  const int aoff = (wr * 128 + fr) * 32 + fo;
  const int boff = (wc * 64 + fr) * 32 + fo;

  f32x4 acc[8][4];
#pragma unroll
  for (int i = 0; i < 8; ++i) {
#pragma unroll
    for (int j = 0; j < 4; ++j) acc[i][j] = (f32x4)0.f;
  }

  const int nk = K >> 5;
  // prologue: stage K-tiles 0 (buf0) and 1 (buf1)
  gld16(gA0, &smem[lw]);
  gld16(gA1, &smem[4096 + lw]);
  gld16(gB0, &smem[8192 + lw]);
  gld16(gB1, &smem[12288 + lw]);
  gld16(gA0 + 32, &smem[16384 + lw]);
  gld16(gA1 + 32, &smem[16384 + 4096 + lw]);
  gld16(gB0 + 32, &smem[16384 + 8192 + lw]);
  gld16(gB1 + 32, &smem[16384 + 12288 + lw]);

  int cur = 0;
  for (int t = 0; t < nk; ++t) {
    if (t < nk - 1)
      asm volatile("s_waitcnt vmcnt(4)" ::: "memory");
    else
      asm volatile("s_waitcnt vmcnt(0)" ::: "memory");
    __builtin_amdgcn_s_barrier();
    __builtin_amdgcn_sched_barrier(0);

    const unsigned short* sA = smem + cur * 16384;
    const unsigned short* sB = sA + 8192;
    int nxt = cur + 2;
    if (nxt >= 3) nxt -= 3;
    unsigned short* nbase = smem + nxt * 16384;
    const bool more = (t + 2) < nk;
    const int kn = (t + 2) << 5;

    // ALL ds_reads for tile t first
    f16x8 b0 = *(const f16x8*)&sB[boff];
    f16x8 b1 = *(const f16x8*)&sB[boff + 512];
    f16x8 b2 = *(const f16x8*)&sB[boff + 1024];
    f16x8 b3 = *(const f16x8*)&sB[boff + 1536];
    f16x8 a0 = *(const f16x8*)&sA[aoff];
    f16x8 a1 = *(const f16x8*)&sA[aoff + 512];
    f16x8 a2 = *(const f16x8*)&sA[aoff + 1024];
    f16x8 a3 = *(const f16x8*)&sA[aoff + 1536];
    f16x8 a4 = *(const f16x8*)&sA[aoff + 2048];
    f16x8 a5 = *(const f16x8*)&sA[aoff + 2560];
    f16x8 a6 = *(const f16x8*)&sA[aoff + 3072];
    f16x8 a7 = *(const f16x8*)&sA[aoff + 3584];
    __builtin_amdgcn_sched_barrier(0);
    // issue tile t+2 loads after the reads
    if (more) {
      gld16(gA0 + kn, nbase + lw);
      gld16(gA1 + kn, nbase + 4096 + lw);
      gld16(gB0 + kn, nbase + 8192 + lw);
      gld16(gB1 + kn, nbase + 12288 + lw);
    }
    __builtin_amdgcn_sched_barrier(0);
    __builtin_amdgcn_s_setprio(1);
    acc[0][0] = MFMA16(a0, b0, acc[0][0]);
    acc[0][1] = MFMA16(a0, b1, acc[0][1]);
    acc[0][2] = MFMA16(a0, b2, acc[0][2]);
    acc[0][3] = MFMA16(a0, b3, acc[0][3]);
    acc[1][0] = MFMA16(a1, b0, acc[1][0]);
    acc[1][1] = MFMA16(a1, b1, acc[1][1]);
    acc[1][2] = MFMA16(a1, b2, acc[1][2]);
    acc[1][3] = MFMA16(a1, b3, acc[1][3]);
    acc[2][0] = MFMA16(a2, b0, acc[2][0]);
    acc[2][1] = MFMA16(a2, b1, acc[2][1]);
    acc[2][2] = MFMA16(a2, b2, acc[2][2]);
    acc[2][3] = MFMA16(a2, b3, acc[2][3]);
    acc[3][0] = MFMA16(a3, b0, acc[3][0]);
    acc[3][1] = MFMA16(a3, b1, acc[3][1]);
    acc[3][2] = MFMA16(a3, b2, acc[3][2]);
    acc[3][3] = MFMA16(a3, b3, acc[3][3]);
    acc[4][0] = MFMA16(a4, b0, acc[4][0]);
    acc[4][1] = MFMA16(a4, b1, acc[4][1]);
    acc[4][2] = MFMA16(a4, b2, acc[4][2]);
    acc[4][3] = MFMA16(a4, b3, acc[4][3]);
    acc[5][0] = MFMA16(a5, b0, acc[5][0]);
    acc[5][1] = MFMA16(a5, b1, acc[5][1]);
    acc[5][2] = MFMA16(a5, b2, acc[5][2]);
    acc[5][3] = MFMA16(a5, b3, acc[5][3]);
    acc[6][0] = MFMA16(a6, b0, acc[6][0]);
    acc[6][1] = MFMA16(a6, b1, acc[6][1]);
    acc[6][2] = MFMA16(a6, b2, acc[6][2]);
    acc[6][3] = MFMA16(a6, b3, acc[6][3]);
    acc[7][0] = MFMA16(a7, b0, acc[7][0]);
    acc[7][1] = MFMA16(a7, b1, acc[7][1]);
    acc[7][2] = MFMA16(a7, b2, acc[7][2]);
    acc[7][3] = MFMA16(a7, b3, acc[7][3]);
    __builtin_amdgcn_s_setprio(0);

    cur += 1;
    if (cur >= 3) cur -= 3;
  }

  // epilogue; frag: D[row=fc*4+i][col=fr]
  if constexpr (EPI == 5) {
    unsigned short* Ch = (unsigned short*)Cv;
    const int Nh = N >> 1;
#pragma unroll
    for (int mi = 0; mi < 8; ++mi) {
#pragma unroll
      for (int p = 0; p < 2; ++p) {
        const int hcol = (((n0 + wc * 64) >> 5) + p) * 16 + fr;
        const int mb = m0 + wr * 128 + mi * 16 + fc * 4;
#pragma unroll
        for (int i = 0; i < 4; ++i) {
          const int m = mb + i;
          float v1 = acc[mi][2 * p][i];
          float v3 = acc[mi][2 * p + 1][i];
          float y = v1 / (1.f + __expf(-v1)) * v3;
          Ch[(size_t)m * Nh + hcol] = f2h(y);
        }
      }
    }
  } else {
    unsigned short* Ch = (unsigned short*)Cv;
#pragma unroll
    for (int mi = 0; mi < 8; ++mi) {
#pragma unroll
      for (int ni = 0; ni < 4; ++ni) {
        const int n = n0 + wc * 64 + ni * 16 + fr;
        const int mb = m0 + wr * 128 + mi * 16 + fc * 4;
#pragma unroll
        for (int i = 0; i < 4; ++i) {
          const int m = mb + i;
          float v = acc[mi][ni][i];
          if (bias) v += bias[n];
          Ch[(size_t)m * N + n] = f2h(v);
        }
      }
    }
  }
}

// ---------------- host ----------------

extern "C" void kernel_launch(void* const* d_in, const int* in_sizes, int n_in,
                              void* d_out, int out_size, void* d_ws, size_t ws_size,
                              hipStream_t stream) {
  (void)in_sizes; (void)n_in; (void)out_size; (void)ws_size;
  const float* hs = (const float*)d_in[0];
  const float* temb = (const float*)d_in[1];
  const float* rope = (const float*)d_in[2];
  const float* adaw = (const float*)d_in[3];
  const float* adab = (const float*)d_in[4];
  const float* qkvw = (const float*)d_in[5];
  const float* qkvb = (const float*)d_in[6];
  const float* qnw = (const float*)d_in[7];
  const float* knw = (const float*)d_in[8];
  const float* outw = (const float*)d_in[9];
  const float* outb = (const float*)d_in[10];
  const float* gatew = (const float*)d_in[11];
  const float* ew1 = (const float*)d_in[12];
  const float* ew2 = (const float*)d_in[13];
  const float* ew3 = (const float*)d_in[14];
  const float* sw1 = (const float*)d_in[15];
  const float* sw2 = (const float*)d_in[16];
  const float* sw3 = (const float*)d_in[17];
  float* out = (float*)d_out;
  char* ws = (char*)d_ws;

  size_t off = 0;
  auto give = [&](size_t nbytes) {
    size_t r = off;
    off += (nbytes + 255) & ~(size_t)255;
    return r;
  };
  const size_t T = T_TOK, D = DIM;
  size_t o_mod = give(15360 * 4);
  size_t o_ss = give(D * 4);
  size_t o_wd = give(T * 4 * 4);
  size_t o_idx = give(MPAD * 4);
  size_t o_seg = give(8 * 4);
  size_t o_slot = give(T * 2 * 4);
  size_t o_wab = give(T * 2 * 4);
  size_t o_nh = give(T * D * 2);      // nh fp16; later nh2
  size_t o_qkvh = give(T * 7680 * 2); // qkv fp16; region later reused as hmid
  size_t o_qh = give(T * D * 2);
  size_t o_kh = give(T * D * 2);
  size_t o_vt = give(T * D * 2);
  size_t o_obf = give(T * D * 2);
  size_t o_h2 = give(T * D * 4);
  size_t o_yc = give((size_t)MPAD * D * 2);       // compact expert outputs fp16
  size_t o_hmid2 = give(T * SHID_E * 2);          // shared-expert mid
  // fp16 weights
  size_t o_qkvw = give((size_t)7680 * 2560 * 2);
  size_t o_outw = give((size_t)2560 * 2560 * 2);
  size_t o_ewA = give((size_t)4 * 2 * HID_E * 2560 * 2);  // interleaved w1/w3
  size_t o_ew2 = give((size_t)4 * 2560 * HID_E * 2);
  size_t o_swA = give((size_t)2 * SHID_E * 2560 * 2);     // interleaved sw1/sw3
  size_t o_sw2 = give((size_t)2560 * SHID_E * 2);

  float* mod = (float*)(ws + o_mod);
  float* ss = (float*)(ws + o_ss);
  float* wd = (float*)(ws + o_wd);
  int* idxb = (int*)(ws + o_idx);
  int* segp = (int*)(ws + o_seg);
  int* slotAB = (int*)(ws + o_slot);
  float* wAB = (float*)(ws + o_wab);
  unsigned short* nh_h = (unsigned short*)(ws + o_nh);
  unsigned short* qkvh = (unsigned short*)(ws + o_qkvh);
  unsigned short* qh = (unsigned short*)(ws + o_qh);
  unsigned short* kh = (unsigned short*)(ws + o_kh);
  unsigned short* vt = (unsigned short*)(ws + o_vt);
  unsigned short* obf = (unsigned short*)(ws + o_obf);
  float* h2 = (float*)(ws + o_h2);
  unsigned short* yc = (unsigned short*)(ws + o_yc);
  unsigned short* hmid2 = (unsigned short*)(ws + o_hmid2);
  unsigned short* qkvw_h = (unsigned short*)(ws + o_qkvw);
  unsigned short* outw_h = (unsigned short*)(ws + o_outw);
  unsigned short* ewA_h = (unsigned short*)(ws + o_ewA);
  unsigned short* ew2_h = (unsigned short*)(ws + o_ew2);
  unsigned short* swA_h = (unsigned short*)(ws + o_swA);
  unsigned short* sw2_h = (unsigned short*)(ws + o_sw2);
  unsigned short* nh2 = nh_h;
  // hmid (MPAD x 6912 fp16 = 70.8 MB) aliases qkvh..obf (73.4 MB), dead after out-proj
  unsigned short* hmid = qkvh;

  // 0) weight conversion f32 -> fp16 (fused) + w1/w3 interleave (fused)
  cvt_all4<<<4096, 256, 0, stream>>>(qkvw, qkvw_h, 7680L * 2560 / 8,
                                     outw, outw_h, 2560L * 2560 / 8,
                                     ew2, ew2_h, 4L * 2560 * HID_E / 8,
                                     sw2, sw2_h, 2560L * SHID_E / 8);
  cvt_pair_all<<<4 * 2 * HID_E + 2 * SHID_E, 256, 0, stream>>>(ew1, ew3, sw1, sw3,
                                                               ewA_h, swA_h);
  // 1) adaLN modulation
  silu_k<<<10, 256, 0, stream>>>(temb, ss);
  adaln_gemv<<<3840, 256, 0, stream>>>(ss, adaw, adab, mod);
  // 2) LN1 + modulate (fp16)
  ln_mod<<<T, 256, 0, stream>>>(hs, mod, mod + D, nh_h);
  // 3) qkv GEMM -> fp16 (256-tile)
  gemm256<4, 0><<<240, 512, 0, stream>>>(nh_h, qkvw_h, qkvb, qkvh,
                                         nullptr, nullptr, 2048, 7680, 2560);
  // 4) RMSNorm + RoPE
  rmsrope<<<T, 256, 0, stream>>>(qkvh, qnw, knw, rope, qh, kh);
  // 5) V transpose
  transpose_v<<<dim3(80, 64), dim3(32, 8), 0, stream>>>(qkvh, vt);
  // 6) MFMA flash attention (two 64-q tiles per block, shared K/V staging)
  fattn<<<dim3(16, 20), 256, 0, stream>>>(qh, kh, vt, obf);
  // 7) out proj + gate_msa residual -> h2 f32
  gemm128<1, 0><<<16 * 20, 256, 0, stream>>>(obf, outw_h, outb, h2,
                                             mod + 2 * D, hs, nullptr, nullptr,
                                             nullptr, nullptr, nullptr, 2048, 2560, 2560);
  // 8) LN2 + modulate + routing, then concatenated 256-padded compaction
  ln2_route<<<T, 256, 0, stream>>>(h2, mod + 3 * D, mod + 4 * D, gatew, nh2, wd);
  route_compact<<<1, 256, 0, stream>>>(wd, idxb, segp, slotAB, wAB);
  // 9) MoE experts: fused w1w3+swiglu 256-tile GEMM + w2 256-tile GEMM
  gemm256<5, 1><<<20 * 54, 512, 0, stream>>>(nh2, ewA_h, nullptr, hmid,
                                             idxb, segp, MPAD, 2 * HID_E, 2560);
  gemm256<4, 2><<<20 * 10, 512, 0, stream>>>(hmid, ew2_h, nullptr, yc,
                                             nullptr, segp, MPAD, 2560, 6912);
  // 10) shared expert (256-tile fused w1w3+swiglu) + final combine w/ yc gather
  gemm256<5, 0><<<8 * 28, 512, 0, stream>>>(nh2, swA_h, nullptr, hmid2,
                                            nullptr, nullptr, 2048, 2 * SHID_E, 2560);
  gemm128<6, 0><<<16 * 20, 256, 0, stream>>>(hmid2, sw2_h, nullptr, out,
                                             mod + 5 * D, h2, nullptr, nullptr,
                                             slotAB, wAB, yc, 2048, 2560, 3584);
}

// Round 13
// 1386.713 us; speedup vs baseline: 1.1006x; 1.1006x over previous
//
#include <hip/hip_runtime.h>

#define DIM 2560
#define T_TOK 2048
#define NHEADS 20
#define HD 128
#define HID_E 6912
#define SHID_E 3584
#define MPAD 5120  // concat rows, segments padded to 256 (max 4096+4*255 <= 5120)

typedef _Float16 f16x8 __attribute__((ext_vector_type(8)));
typedef float f32x4 __attribute__((ext_vector_type(4)));
typedef unsigned short u16x8 __attribute__((ext_vector_type(8)));

#define MFMA16(a, b, c) __builtin_amdgcn_mfma_f32_16x16x32_f16((a), (b), (c), 0, 0, 0)

__device__ inline unsigned short f2h(float f) {
  return __builtin_bit_cast(unsigned short, (_Float16)f);
}
__device__ inline float h2f(unsigned short u) {
  return (float)__builtin_bit_cast(_Float16, u);
}
__device__ inline float wave_sum(float v) {
#pragma unroll
  for (int off = 32; off > 0; off >>= 1) v += __shfl_down(v, off, 64);
  return v;
}
// async global->LDS, 16B per lane; LDS dest = wave-uniform base + lane*16
__device__ inline void gld16(const void* g, void* l) {
  __builtin_amdgcn_global_load_lds((const __attribute__((address_space(1))) void*)g,
                                   (__attribute__((address_space(3))) void*)l, 16, 0, 0);
}

// ---------------- tiny kernels ----------------

__global__ __launch_bounds__(256) void silu_k(const float* __restrict__ t,
                                              float* __restrict__ ss) {
  int i = blockIdx.x * 256 + threadIdx.x;
  if (i < DIM) {
    float v = t[i];
    ss[i] = v / (1.f + expf(-v));
  }
}

// fused f32->fp16 conversion over 4 segments (n in groups of 8)
__global__ __launch_bounds__(256) void cvt_all4(
    const float* __restrict__ s0, unsigned short* __restrict__ d0, long n0,
    const float* __restrict__ s1, unsigned short* __restrict__ d1, long n1,
    const float* __restrict__ s2, unsigned short* __restrict__ d2, long n2,
    const float* __restrict__ s3, unsigned short* __restrict__ d3, long n3) {
  const long stride = (long)gridDim.x * 256;
  const long t01 = n0 + n1, t012 = t01 + n2, tot = t012 + n3;
  for (long i = (long)blockIdx.x * 256 + threadIdx.x; i < tot; i += stride) {
    const float* s;
    unsigned short* d;
    long j;
    if (i < n0) { s = s0; d = d0; j = i; }
    else if (i < t01) { s = s1; d = d1; j = i - n0; }
    else if (i < t012) { s = s2; d = d2; j = i - t01; }
    else { s = s3; d = d3; j = i - t012; }
    float4 a = *(const float4*)(s + j * 8);
    float4 b = *(const float4*)(s + j * 8 + 4);
    u16x8 u;
    u[0] = f2h(a.x); u[1] = f2h(a.y); u[2] = f2h(a.z); u[3] = f2h(a.w);
    u[4] = f2h(b.x); u[5] = f2h(b.y); u[6] = f2h(b.z); u[7] = f2h(b.w);
    *(u16x8*)&d[j * 8] = u;
  }
}

// fused w1/w3 interleave for all 4 experts + shared.
// row j of output group: (j&31)<16 ? w1[(j>>5)*16+(j&15)] : w3[(j>>5)*16+(j&15)]
__global__ __launch_bounds__(256) void cvt_pair_all(
    const float* __restrict__ ew1, const float* __restrict__ ew3,
    const float* __restrict__ sw1, const float* __restrict__ sw3,
    unsigned short* __restrict__ ewA, unsigned short* __restrict__ swA) {
  const int j = blockIdx.x;
  const float *w1, *w3;
  unsigned short* dst;
  int row;
  if (j < 4 * 2 * HID_E) {
    const int e = j / (2 * HID_E);
    row = j - e * 2 * HID_E;
    w1 = ew1 + (size_t)e * HID_E * DIM;
    w3 = ew3 + (size_t)e * HID_E * DIM;
    dst = ewA + (size_t)e * 2 * HID_E * DIM + (size_t)row * DIM;
  } else {
    row = j - 4 * 2 * HID_E;
    w1 = sw1;
    w3 = sw3;
    dst = swA + (size_t)row * DIM;
  }
  const int g = row >> 5, r = row & 31;
  const float* src = (r < 16) ? (w1 + (size_t)(g * 16 + r) * DIM)
                              : (w3 + (size_t)(g * 16 + (r & 15)) * DIM);
  for (int i = threadIdx.x; i < 320; i += 256) {
    float4 a = *(const float4*)(src + i * 8);
    float4 b = *(const float4*)(src + i * 8 + 4);
    u16x8 u;
    u[0] = f2h(a.x); u[1] = f2h(a.y); u[2] = f2h(a.z); u[3] = f2h(a.w);
    u[4] = f2h(b.x); u[5] = f2h(b.y); u[6] = f2h(b.z); u[7] = f2h(b.w);
    *(u16x8*)&dst[i * 8] = u;
  }
}

// mod[j] = dot(silu(temb), adaln_w[j]) + adaln_b[j]; one wave per output
__global__ __launch_bounds__(256) void adaln_gemv(const float* __restrict__ ss,
                                                  const float* __restrict__ W,
                                                  const float* __restrict__ bias,
                                                  float* __restrict__ mod) {
  const int lane = threadIdx.x & 63;
  const int j = blockIdx.x * 4 + (threadIdx.x >> 6);
  const float* wr = W + (size_t)j * DIM;
  float p = 0.f;
  for (int i = lane; i < 640; i += 64) {
    float4 w = *(const float4*)(wr + i * 4);
    float4 x = *(const float4*)(ss + i * 4);
    p += w.x * x.x + w.y * x.y + w.z * x.z + w.w * x.w;
  }
  p = wave_sum(p);
  if (lane == 0) mod[j] = p + bias[j];
}

// LN (no affine) then *(1+scale)+shift, write fp16. One block per row.
__global__ __launch_bounds__(256) void ln_mod(const float* __restrict__ x,
                                              const float* __restrict__ shift,
                                              const float* __restrict__ scale,
                                              unsigned short* __restrict__ outp) {
  __shared__ float rbuf[8];
  const int t = blockIdx.x, tid = threadIdx.x, lane = tid & 63, wid = tid >> 6;
  const float* xr = x + (size_t)t * DIM;
  float s = 0.f, sq = 0.f;
  for (int i = tid; i < 640; i += 256) {
    float4 v = *(const float4*)(xr + i * 4);
    s += v.x + v.y + v.z + v.w;
    sq += v.x * v.x + v.y * v.y + v.z * v.z + v.w * v.w;
  }
  s = wave_sum(s);
  sq = wave_sum(sq);
  if (lane == 0) {
    rbuf[wid] = s;
    rbuf[4 + wid] = sq;
  }
  __syncthreads();
  float S = rbuf[0] + rbuf[1] + rbuf[2] + rbuf[3];
  float SQ = rbuf[4] + rbuf[5] + rbuf[6] + rbuf[7];
  float mean = S * (1.f / DIM);
  float rs = rsqrtf(SQ * (1.f / DIM) - mean * mean + 1e-6f);
  for (int i = tid; i < 640; i += 256) {
    float4 v = *(const float4*)(xr + i * 4);
    float4 sc4 = *(const float4*)(scale + i * 4);
    float4 sh4 = *(const float4*)(shift + i * 4);
    ushort4 u;
    u.x = f2h((v.x - mean) * rs * (1.f + sc4.x) + sh4.x);
    u.y = f2h((v.y - mean) * rs * (1.f + sc4.y) + sh4.y);
    u.z = f2h((v.z - mean) * rs * (1.f + sc4.z) + sh4.z);
    u.w = f2h((v.w - mean) * rs * (1.f + sc4.w) + sh4.w);
    *(ushort4*)&outp[(size_t)t * DIM + i * 4] = u;
  }
}

// RMSNorm(q),(k) over full 2560 + weight + RoPE -> qh (scaled by 1/sqrt(128)), kh
__global__ __launch_bounds__(256) void rmsrope(const unsigned short* __restrict__ qkv,
                                               const float* __restrict__ qn,
                                               const float* __restrict__ kn,
                                               const float* __restrict__ rope,
                                               unsigned short* __restrict__ qh,
                                               unsigned short* __restrict__ kh) {
  __shared__ float rbuf[8];
  const int t = blockIdx.x, tid = threadIdx.x, lane = tid & 63, wid = tid >> 6;
  const unsigned short* row = qkv + (size_t)t * 7680;
  float sq = 0.f, sk = 0.f;
  for (int i = tid; i < 320; i += 256) {
    f16x8 qv = *(const f16x8*)(row + i * 8);
    f16x8 kv = *(const f16x8*)(row + DIM + i * 8);
#pragma unroll
    for (int j = 0; j < 8; ++j) {
      float q = (float)qv[j], k = (float)kv[j];
      sq += q * q;
      sk += k * k;
    }
  }
  sq = wave_sum(sq);
  sk = wave_sum(sk);
  if (lane == 0) {
    rbuf[wid] = sq;
    rbuf[4 + wid] = sk;
  }
  __syncthreads();
  float SQ = rbuf[0] + rbuf[1] + rbuf[2] + rbuf[3];
  float SK = rbuf[4] + rbuf[5] + rbuf[6] + rbuf[7];
  float rq = rsqrtf(SQ * (1.f / DIM) + 1e-6f) * 0.08838834764831845f;
  float rk = rsqrtf(SK * (1.f / DIM) + 1e-6f);
  for (int pp = tid; pp < 1280; pp += 256) {
    int c = pp * 2;
    float qe = h2f(row[c]) * rq * qn[c], qo = h2f(row[c + 1]) * rq * qn[c + 1];
    float ke = h2f(row[DIM + c]) * rk * kn[c], ko = h2f(row[DIM + c + 1]) * rk * kn[c + 1];
    float4 rr = *(const float4*)(rope + (size_t)t * 256 + (pp & 63) * 4);
    unsigned qp = (unsigned)f2h(rr.x * qe + rr.y * qo) |
                  ((unsigned)f2h(rr.z * qe + rr.w * qo) << 16);
    unsigned kp = (unsigned)f2h(rr.x * ke + rr.y * ko) |
                  ((unsigned)f2h(rr.z * ke + rr.w * ko) << 16);
    *(unsigned*)&qh[(size_t)t * DIM + c] = qp;
    *(unsigned*)&kh[(size_t)t * DIM + c] = kp;
  }
}

// V part of qkv (fp16 [2048][7680] at col 5120) -> vt fp16 [2560][2048]
__global__ void transpose_v(const unsigned short* __restrict__ in,
                            unsigned short* __restrict__ outp) {
  __shared__ unsigned short tile[32][33];
  const int bx = blockIdx.x * 32;  // channel
  const int by = blockIdx.y * 32;  // token
  const int tx = threadIdx.x, ty = threadIdx.y;
  for (int j = ty; j < 32; j += 8)
    tile[j][tx] = in[(size_t)(by + j) * 7680 + 5120 + bx + tx];
  __syncthreads();
  for (int j = ty; j < 32; j += 8)
    outp[(size_t)(bx + j) * T_TOK + by + tx] = tile[tx][j];
}

// ---------------- MFMA flash attention (single 64-q tile per block) ----------------
__global__ __launch_bounds__(256) void fattn(const unsigned short* __restrict__ qh,
                                             const unsigned short* __restrict__ kh,
                                             const unsigned short* __restrict__ vt,
                                             unsigned short* __restrict__ obuf) {
  __shared__ unsigned short sK[64 * 128];  // [k][d], slot = c ^ (r&15)
  __shared__ unsigned short sV[128 * 64];  // [d][k], slot = c ^ (r&7)
  __shared__ unsigned short sP[64 * 64];   // [q][k], slot = c ^ (r&7)
  __shared__ float sRedM[4][64];
  __shared__ float sRedL[4][64];
  __shared__ float sM[64];
  __shared__ float sL[64];
  const int tid = threadIdx.x, lane = tid & 63, wv = tid >> 6;
  const int g = lane >> 4, fr = lane & 15;
  const int h = blockIdx.y;
  const int q0 = blockIdx.x * 64;

  {
    const int r = tid >> 2, qt = tid & 3;
    const unsigned short* gp = qh + (size_t)(q0 + r) * DIM + h * HD + qt * 32;
    uint4 v0 = ((const uint4*)gp)[0];
    uint4 v1 = ((const uint4*)gp)[1];
    uint4 v2 = ((const uint4*)gp)[2];
    uint4 v3 = ((const uint4*)gp)[3];
    unsigned short* dst = &sK[r * 128];
    const int cb = qt * 4, rs = r & 15;
    *(uint4*)&dst[((cb + 0) ^ rs) * 8] = v0;
    *(uint4*)&dst[((cb + 1) ^ rs) * 8] = v1;
    *(uint4*)&dst[((cb + 2) ^ rs) * 8] = v2;
    *(uint4*)&dst[((cb + 3) ^ rs) * 8] = v3;
  }
  __syncthreads();
  f16x8 qfrag[4][4];
#pragma unroll
  for (int ni = 0; ni < 4; ++ni) {
#pragma unroll
    for (int kt = 0; kt < 4; ++kt) {
      int r = ni * 16 + fr;
      qfrag[ni][kt] = *(const f16x8*)&sK[r * 128 + (((kt * 4 + g) ^ (r & 15)) << 3)];
    }
  }
  __syncthreads();

  f32x4 acco[4][2];
  f32x4 mprev[4];
  float mrun[4], lrun[4];
#pragma unroll
  for (int i = 0; i < 4; ++i) {
    acco[i][0] = (f32x4)0.f;
    acco[i][1] = (f32x4)0.f;
    mprev[i] = (f32x4)(-1e30f);
    mrun[i] = -1e30f;
    lrun[i] = 0.f;
  }

  for (int kt0 = 0; kt0 < T_TOK; kt0 += 64) {
    {
      const int r = tid >> 2, qt = tid & 3;
      const unsigned short* gp = kh + (size_t)(kt0 + r) * DIM + h * HD + qt * 32;
      uint4 v0 = ((const uint4*)gp)[0];
      uint4 v1 = ((const uint4*)gp)[1];
      uint4 v2 = ((const uint4*)gp)[2];
      uint4 v3 = ((const uint4*)gp)[3];
      unsigned short* dst = &sK[r * 128];
      const int cb = qt * 4, rs = r & 15;
      *(uint4*)&dst[((cb + 0) ^ rs) * 8] = v0;
      *(uint4*)&dst[((cb + 1) ^ rs) * 8] = v1;
      *(uint4*)&dst[((cb + 2) ^ rs) * 8] = v2;
      *(uint4*)&dst[((cb + 3) ^ rs) * 8] = v3;
      const int rv = tid >> 1, hf = tid & 1;
      const unsigned short* gv = vt + (size_t)(h * HD + rv) * T_TOK + kt0 + hf * 32;
      uint4 w0 = ((const uint4*)gv)[0];
      uint4 w1 = ((const uint4*)gv)[1];
      uint4 w2 = ((const uint4*)gv)[2];
      uint4 w3 = ((const uint4*)gv)[3];
      unsigned short* dv = &sV[rv * 64];
      const int cv = hf * 4, rvs = rv & 7;
      *(uint4*)&dv[((cv + 0) ^ rvs) * 8] = w0;
      *(uint4*)&dv[((cv + 1) ^ rvs) * 8] = w1;
      *(uint4*)&dv[((cv + 2) ^ rvs) * 8] = w2;
      *(uint4*)&dv[((cv + 3) ^ rvs) * 8] = w3;
    }
    __syncthreads();  // B0

    f32x4 accs[4] = {(f32x4)0.f, (f32x4)0.f, (f32x4)0.f, (f32x4)0.f};
#pragma unroll
    for (int kt = 0; kt < 4; ++kt) {
      int r = wv * 16 + fr;
      f16x8 ak = *(const f16x8*)&sK[r * 128 + (((kt * 4 + g) ^ (r & 15)) << 3)];
#pragma unroll
      for (int ni = 0; ni < 4; ++ni) accs[ni] = MFMA16(ak, qfrag[ni][kt], accs[ni]);
    }

    float pm[4];
#pragma unroll
    for (int ni = 0; ni < 4; ++ni) {
      float m = fmaxf(fmaxf(accs[ni][0], accs[ni][1]), fmaxf(accs[ni][2], accs[ni][3]));
      m = fmaxf(m, __shfl_xor(m, 16));
      m = fmaxf(m, __shfl_xor(m, 32));
      pm[ni] = m;
    }
    if (g == 0) {
#pragma unroll
      for (int ni = 0; ni < 4; ++ni) sRedM[wv][ni * 16 + fr] = pm[ni];
    }
    __syncthreads();  // B1
    float mnew[4];
#pragma unroll
    for (int ni = 0; ni < 4; ++ni) {
      int q = ni * 16 + fr;
      float mt = fmaxf(fmaxf(sRedM[0][q], sRedM[1][q]), fmaxf(sRedM[2][q], sRedM[3][q]));
      mnew[ni] = fmaxf(mrun[ni], mt);
    }
    float lsum[4];
#pragma unroll
    for (int ni = 0; ni < 4; ++ni) {
      float l0 = 0.f;
#pragma unroll
      for (int i = 0; i < 4; ++i) {
        float p = __expf(accs[ni][i] - mnew[ni]);
        accs[ni][i] = p;
        l0 += p;
      }
      l0 += __shfl_xor(l0, 16);
      l0 += __shfl_xor(l0, 32);
      lsum[ni] = l0;
    }
    if (g == 0) {
#pragma unroll
      for (int ni = 0; ni < 4; ++ni) sRedL[wv][ni * 16 + fr] = lsum[ni];
      if (wv == 0) {
#pragma unroll
        for (int ni = 0; ni < 4; ++ni) sM[ni * 16 + fr] = mnew[ni];
      }
    }
#pragma unroll
    for (int ni = 0; ni < 4; ++ni) {
      int q = ni * 16 + fr;
      unsigned p01 = (unsigned)f2h(accs[ni][0]) | ((unsigned)f2h(accs[ni][1]) << 16);
      unsigned p23 = (unsigned)f2h(accs[ni][2]) | ((unsigned)f2h(accs[ni][3]) << 16);
      uint2 pk;
      pk.x = p01;
      pk.y = p23;
      *(uint2*)&sP[q * 64 + ((((wv << 1) | (g >> 1)) ^ (q & 7)) << 3) + ((g & 1) << 2)] = pk;
    }
    __syncthreads();  // B2
#pragma unroll
    for (int ni = 0; ni < 4; ++ni) {
      int q = ni * 16 + fr;
      float lt = sRedL[0][q] + sRedL[1][q] + sRedL[2][q] + sRedL[3][q];
      lrun[ni] = lrun[ni] * __expf(mrun[ni] - mnew[ni]) + lt;
      mrun[ni] = mnew[ni];
    }

#pragma unroll
    for (int mi = 0; mi < 4; ++mi) {
      f32x4 mn = *(const f32x4*)&sM[mi * 16 + g * 4];
      f32x4 sc;
#pragma unroll
      for (int i = 0; i < 4; ++i) sc[i] = __expf(mprev[mi][i] - mn[i]);
      acco[mi][0] *= sc;
      acco[mi][1] *= sc;
      mprev[mi] = mn;
    }
#pragma unroll
    for (int ktp = 0; ktp < 2; ++ktp) {
      f16x8 bv[2];
#pragma unroll
      for (int nd = 0; nd < 2; ++nd) {
        int r = wv * 32 + nd * 16 + fr;
        bv[nd] = *(const f16x8*)&sV[r * 64 + (((ktp * 4 + g) ^ (r & 7)) << 3)];
      }
#pragma unroll
      for (int mi = 0; mi < 4; ++mi) {
        int r = mi * 16 + fr;
        f16x8 ap = *(const f16x8*)&sP[r * 64 + (((ktp * 4 + g) ^ (r & 7)) << 3)];
        acco[mi][0] = MFMA16(ap, bv[0], acco[mi][0]);
        acco[mi][1] = MFMA16(ap, bv[1], acco[mi][1]);
      }
    }
    __syncthreads();  // B3
  }

  if (wv == 0 && g == 0) {
#pragma unroll
    for (int ni = 0; ni < 4; ++ni) sL[ni * 16 + fr] = 1.f / lrun[ni];
  }
  __syncthreads();
#pragma unroll
  for (int mi = 0; mi < 4; ++mi) {
    f32x4 li = *(const f32x4*)&sL[mi * 16 + g * 4];
#pragma unroll
    for (int nd = 0; nd < 2; ++nd) {
#pragma unroll
      for (int i = 0; i < 4; ++i) {
        float o = acco[mi][nd][i] * li[i];
        obuf[(size_t)(q0 + mi * 16 + g * 4 + i) * DIM + h * HD + wv * 32 + nd * 16 + fr] =
            f2h(o);
      }
    }
  }
}

// LN2 + modulate -> nh2 fp16, plus f32 routing (softmax over 4, top-2, unnormalized)
__global__ __launch_bounds__(256) void ln2_route(const float* __restrict__ x,
                                                 const float* __restrict__ shift,
                                                 const float* __restrict__ scale,
                                                 const float* __restrict__ gw,
                                                 unsigned short* __restrict__ nh2,
                                                 float* __restrict__ wd) {
  __shared__ float rbuf[8];
  __shared__ float gbuf[4][4];
  const int t = blockIdx.x, tid = threadIdx.x, lane = tid & 63, wid = tid >> 6;
  const float* xr = x + (size_t)t * DIM;
  float s = 0.f, sq = 0.f;
  for (int i = tid; i < 640; i += 256) {
    float4 v = *(const float4*)(xr + i * 4);
    s += v.x + v.y + v.z + v.w;
    sq += v.x * v.x + v.y * v.y + v.z * v.z + v.w * v.w;
  }
  s = wave_sum(s);
  sq = wave_sum(sq);
  if (lane == 0) {
    rbuf[wid] = s;
    rbuf[4 + wid] = sq;
  }
  __syncthreads();
  float S = rbuf[0] + rbuf[1] + rbuf[2] + rbuf[3];
  float SQ = rbuf[4] + rbuf[5] + rbuf[6] + rbuf[7];
  float mean = S * (1.f / DIM);
  float rs = rsqrtf(SQ * (1.f / DIM) - mean * mean + 1e-6f);
  float g0 = 0.f, g1 = 0.f, g2 = 0.f, g3 = 0.f;
  for (int i = tid; i < 640; i += 256) {
    float4 v = *(const float4*)(xr + i * 4);
    float4 sc4 = *(const float4*)(scale + i * 4);
    float4 sh4 = *(const float4*)(shift + i * 4);
    float y0 = (v.x - mean) * rs * (1.f + sc4.x) + sh4.x;
    float y1 = (v.y - mean) * rs * (1.f + sc4.y) + sh4.y;
    float y2 = (v.z - mean) * rs * (1.f + sc4.z) + sh4.z;
    float y3 = (v.w - mean) * rs * (1.f + sc4.w) + sh4.w;
    ushort4 u;
    u.x = f2h(y0); u.y = f2h(y1); u.z = f2h(y2); u.w = f2h(y3);
    *(ushort4*)&nh2[(size_t)t * DIM + i * 4] = u;
    float4 w0 = *(const float4*)(gw + i * 4);
    float4 w1 = *(const float4*)(gw + DIM + i * 4);
    float4 w2 = *(const float4*)(gw + 2 * DIM + i * 4);
    float4 w3 = *(const float4*)(gw + 3 * DIM + i * 4);
    g0 += y0 * w0.x + y1 * w0.y + y2 * w0.z + y3 * w0.w;
    g1 += y0 * w1.x + y1 * w1.y + y2 * w1.z + y3 * w1.w;
    g2 += y0 * w2.x + y1 * w2.y + y2 * w2.z + y3 * w2.w;
    g3 += y0 * w3.x + y1 * w3.y + y2 * w3.z + y3 * w3.w;
  }
  g0 = wave_sum(g0);
  g1 = wave_sum(g1);
  g2 = wave_sum(g2);
  g3 = wave_sum(g3);
  if (lane == 0) {
    gbuf[wid][0] = g0; gbuf[wid][1] = g1; gbuf[wid][2] = g2; gbuf[wid][3] = g3;
  }
  __syncthreads();
  if (tid == 0) {
    float l[4];
#pragma unroll
    for (int e = 0; e < 4; ++e) l[e] = gbuf[0][e] + gbuf[1][e] + gbuf[2][e] + gbuf[3][e];
    float mx = fmaxf(fmaxf(l[0], l[1]), fmaxf(l[2], l[3]));
    float ex[4], sum = 0.f;
#pragma unroll
    for (int e = 0; e < 4; ++e) { ex[e] = expf(l[e] - mx); sum += ex[e]; }
    float p[4];
#pragma unroll
    for (int e = 0; e < 4; ++e) p[e] = ex[e] / sum;
    int i1 = 0;
    for (int e = 1; e < 4; ++e)
      if (p[e] > p[i1]) i1 = e;
    int i2 = -1;
    for (int e = 0; e < 4; ++e) {
      if (e == i1) continue;
      if (i2 < 0 || p[e] > p[i2]) i2 = e;
    }
    float w[4] = {0.f, 0.f, 0.f, 0.f};
    w[i1] = p[i1];
    w[i2] = p[i2];
    *(float4*)&wd[(size_t)t * 4] = make_float4(w[0], w[1], w[2], w[3]);
  }
}

// Concatenated padded top-2 compaction. One block, 256 threads, 8 tokens each.
// Segments padded to 256 (for the 256-tile GEMM). idx pad rows point at token 0.
__global__ __launch_bounds__(256) void route_compact(const float* __restrict__ wd,
                                                     int* __restrict__ idx_all,
                                                     int* __restrict__ seg,
                                                     int* __restrict__ slotAB,
                                                     float* __restrict__ wAB) {
  __shared__ unsigned short c[256][4];
  __shared__ int offs[256][4];
  __shared__ int segs[5];
  const int t = threadIdx.x;
  for (int i = t; i < MPAD; i += 256) idx_all[i] = 0;
  unsigned char sel[8];
  float wv4[8][4];
  unsigned short lc[4] = {0, 0, 0, 0};
#pragma unroll
  for (int k = 0; k < 8; ++k) {
    int tok = t * 8 + k;
    float4 w = *(const float4*)&wd[(size_t)tok * 4];
    wv4[k][0] = w.x; wv4[k][1] = w.y; wv4[k][2] = w.z; wv4[k][3] = w.w;
    unsigned m = 0;
    if (w.x != 0.f) { m |= 1; lc[0]++; }
    if (w.y != 0.f) { m |= 2; lc[1]++; }
    if (w.z != 0.f) { m |= 4; lc[2]++; }
    if (w.w != 0.f) { m |= 8; lc[3]++; }
    sel[k] = (unsigned char)m;
  }
#pragma unroll
  for (int e = 0; e < 4; ++e) c[t][e] = lc[e];
  __syncthreads();
  if (t == 0) {
    int run[4] = {0, 0, 0, 0};
    for (int i = 0; i < 256; ++i) {
#pragma unroll
      for (int e = 0; e < 4; ++e) {
        offs[i][e] = run[e];
        run[e] += c[i][e];
      }
    }
    int s = 0;
    segs[0] = 0;
#pragma unroll
    for (int e = 0; e < 4; ++e) {
      s += (run[e] + 255) & ~255;
      segs[e + 1] = s;
    }
#pragma unroll
    for (int e = 0; e < 5; ++e) seg[e] = segs[e];
  }
  __syncthreads();
  int o[4];
#pragma unroll
  for (int e = 0; e < 4; ++e) o[e] = segs[e] + offs[t][e];
#pragma unroll
  for (int k = 0; k < 8; ++k) {
    int tok = t * 8 + k;
    unsigned m = sel[k];
    int sl[2] = {0, 0};
    float sw[2] = {0.f, 0.f};
    int ns = 0;
#pragma unroll
    for (int e = 0; e < 4; ++e) {
      if ((m >> e) & 1) {
        if (ns < 2) { sl[ns] = o[e]; sw[ns] = wv4[k][e]; }
        idx_all[o[e]++] = tok;
        ns++;
      }
    }
    if (ns == 1) { sl[1] = sl[0]; sw[1] = 0.f; }
    slotAB[tok * 2] = sl[0];
    slotAB[tok * 2 + 1] = sl[1];
    wAB[tok * 2] = sw[0];
    wAB[tok * 2 + 1] = sw[1];
  }
}

// ---------------- gemm128: kept for out-proj / final (epilogue-heavy) ----------------
// EPI: 1 f32 aux0[n]*(v+bias)+aux1 | 4 fp16(+bias) |
//      6 final: aux0[n]*(v + wA*yc[slA]+wB*yc[slB]) + aux1
template <int EPI, int MODE>
__global__ __launch_bounds__(256) void gemm128(
    const unsigned short* __restrict__ A, const unsigned short* __restrict__ B,
    const float* __restrict__ bias, void* __restrict__ Cv,
    const float* __restrict__ aux0, const float* __restrict__ aux1,
    const int* __restrict__ idx, const int* __restrict__ seg,
    const int* __restrict__ slotAB, const float* __restrict__ wAB,
    const unsigned short* __restrict__ yc, int M, int N, int K) {
  __shared__ unsigned short smem[16384];  // 2 bufs x (A 4096 + B 4096)
  const int tid = threadIdx.x;
  const int lane = tid & 63;
  const int wv = tid >> 6;
  const int nwg = gridDim.x;
  const int bid = blockIdx.x;
  const int swzb = (bid & 7) * (nwg >> 3) + (bid >> 3);
  const int gm = M >> 7;
  const int m0 = (swzb % gm) * 128, n0 = (swzb / gm) * 128;
  if (MODE != 0 && m0 >= seg[4]) return;

  const unsigned short* Bp = B;
  if constexpr (MODE != 0) {
    int e = 0;
#pragma unroll
    for (int i = 1; i < 4; ++i)
      if (m0 >= seg[i]) e = i;
    Bp = B + (size_t)e * N * K;
  }

  const int wm = (wv >> 1) * 64, wn = (wv & 1) * 64;
  const int fr = lane & 15, fc = lane >> 4;

  const int rl = lane >> 2, ch = lane & 3;
  const int R1 = wv * 16 + rl;
  const int R2 = 64 + R1;
  const int co1 = ((ch ^ ((R1 >> 1) & 3)) << 3);
  const int co2 = ((ch ^ ((R2 >> 1) & 3)) << 3);
  const size_t ar1 = (size_t)(m0 + R1) * K;
  const size_t ar2 = (size_t)(m0 + R2) * K;
  const unsigned short* gA1 = A + ar1 + co1;
  const unsigned short* gA2 = A + ar2 + co2;
  const unsigned short* gB1 = Bp + (size_t)(n0 + R1) * K + co1;
  const unsigned short* gB2 = Bp + (size_t)(n0 + R2) * K + co2;
  const int lA1 = (wv * 16) * 32, lA2 = (64 + wv * 16) * 32;

  f32x4 acc[4][4];
#pragma unroll
  for (int i = 0; i < 4; ++i) {
#pragma unroll
    for (int j = 0; j < 4; ++j) acc[i][j] = (f32x4)0.f;
  }

  auto STAGE = [&](int buf, int kt) {
    unsigned short* base = smem + buf * 8192;
    gld16(gA1 + kt, base + lA1);
    gld16(gA2 + kt, base + lA2);
    gld16(gB1 + kt, base + 4096 + lA1);
    gld16(gB2 + kt, base + 4096 + lA2);
  };
  auto COMPUTE = [&](int buf) {
    const unsigned short* sA = smem + buf * 8192;
    const unsigned short* sB = sA + 4096;
    f16x8 a[4], b[4];
#pragma unroll
    for (int mi = 0; mi < 4; ++mi) {
      int r = wm + mi * 16 + fr;
      a[mi] = *(const f16x8*)&sA[r * 32 + ((fc ^ ((r >> 1) & 3)) << 3)];
    }
#pragma unroll
    for (int ni = 0; ni < 4; ++ni) {
      int r = wn + ni * 16 + fr;
      b[ni] = *(const f16x8*)&sB[r * 32 + ((fc ^ ((r >> 1) & 3)) << 3)];
    }
#pragma unroll
    for (int mi = 0; mi < 4; ++mi) {
#pragma unroll
      for (int ni = 0; ni < 4; ++ni) acc[mi][ni] = MFMA16(a[mi], b[ni], acc[mi][ni]);
    }
  };

  const int nk = K >> 5;
  STAGE(0, 0);
  __syncthreads();
  int cur = 0;
  for (int t = 1; t < nk; ++t) {
    STAGE(cur ^ 1, t << 5);
    COMPUTE(cur);
    __syncthreads();
    cur ^= 1;
  }
  COMPUTE(cur);

#pragma unroll
  for (int mi = 0; mi < 4; ++mi) {
#pragma unroll
    for (int ni = 0; ni < 4; ++ni) {
      const int n = n0 + wn + ni * 16 + fr;
      const int mb = m0 + wm + mi * 16 + fc * 4;
#pragma unroll
      for (int i = 0; i < 4; ++i) {
        const int m = mb + i;
        float v = acc[mi][ni][i];
        const size_t cidx = (size_t)m * N + n;
        if constexpr (EPI == 1) {
          ((float*)Cv)[cidx] = aux0[n] * (v + bias[n]) + aux1[cidx];
        } else if constexpr (EPI == 4) {
          if (bias) v += bias[n];
          ((unsigned short*)Cv)[cidx] = f2h(v);
        } else if constexpr (EPI == 6) {
          const int sA_ = slotAB[m * 2], sB_ = slotAB[m * 2 + 1];
          const float wA_ = wAB[m * 2], wB_ = wAB[m * 2 + 1];
          float vm = wA_ * h2f(yc[(size_t)sA_ * N + n]) + wB_ * h2f(yc[(size_t)sB_ * N + n]);
          ((float*)Cv)[cidx] = aux0[n] * (v + vm) + aux1[cidx];
        }
      }
    }
  }
}

// ---------------- gemm256: 256x256 tile, 8 waves, BK=32, depth-2 counted pipeline ----------
// LDS 96KB: 3 bufs. Per iteration: s_waitcnt vmcnt(4) (tile t done, t+1 in flight) + raw
// s_barrier; 4 MFMA phases read buf[t%3] while issuing tile t+2 into buf[(t+2)%3]
// (A in ph0, B in ph1). vmcnt never drains to 0 in the loop (T4).
// MODE: 0 dense | 1 gather: A rows = idx[m], B by 256-aligned seg | 2 direct A, B by seg.
// EPI: 4 fp16(+bias) | 5 fused swiglu -> fp16, Nh=N/2
template <int EPI, int MODE>
__global__ __launch_bounds__(512) void gemm256(
    const unsigned short* __restrict__ A, const unsigned short* __restrict__ B,
    const float* __restrict__ bias, void* __restrict__ Cv,
    const int* __restrict__ idx, const int* __restrict__ seg,
    int M, int N, int K) {
  __shared__ unsigned short smem[49152];  // 3 bufs x 16384 shorts (32KB each)
  const int tid = threadIdx.x;
  const int lane = tid & 63;
  const int wv = tid >> 6;           // 0..7
  const int wr = wv >> 2;            // 0..1 (m half)
  const int wc = wv & 3;             // 0..3 (n quarter)
  const int fr = lane & 15, fc = lane >> 4;

  const int nwg = gridDim.x;
  const int bid = blockIdx.x;
  const int swzb = (bid & 7) * (nwg >> 3) + (bid >> 3);
  const int gm = M >> 8;
  const int m0 = (swzb % gm) * 256, n0 = (swzb / gm) * 256;
  if (MODE != 0 && m0 >= seg[4]) return;

  const unsigned short* Bp = B;
  if constexpr (MODE != 0) {
    int e = 0;
#pragma unroll
    for (int i = 1; i < 4; ++i)
      if (m0 >= seg[i]) e = i;
    Bp = B + (size_t)e * N * K;
  }

  // staging: per K-tile 4 gld16/wave: A rows [wv*16,+16) of each 128-half, same for B.
  const int srow = (lane >> 2);            // 0..15 within 16-row group
  const int srcc = ((lane & 3) ^ ((lane >> 3) & 3)) << 3;  // pre-swizzled chunk (shorts)
  int mr0, mr1;
  if constexpr (MODE == 1) {
    mr0 = idx[m0 + wv * 16 + srow];
    mr1 = idx[m0 + 128 + wv * 16 + srow];
  } else {
    mr0 = m0 + wv * 16 + srow;
    mr1 = m0 + 128 + wv * 16 + srow;
  }
  const unsigned short* gA0 = A + (size_t)mr0 * K + srcc;
  const unsigned short* gA1 = A + (size_t)mr1 * K + srcc;
  const unsigned short* gB0 = Bp + (size_t)(n0 + wv * 16 + srow) * K + srcc;
  const unsigned short* gB1 = Bp + (size_t)(n0 + 128 + wv * 16 + srow) * K + srcc;
  const int lw = wv << 9;  // wv*16 rows * 32 shorts

  // fragment read offsets (shorts); frag stride = 16 rows * 32 = 512
  const int sw = (fr >> 1) & 3;
  const int fo = ((fc ^ sw) << 3);
  const int aoff = (wr * 128 + fr) * 32 + fo;
  const int boff = (wc * 64 + fr) * 32 + fo;

  f32x4 acc[8][4];
#pragma unroll
  for (int i = 0; i < 8; ++i) {
#pragma unroll
    for (int j = 0; j < 4; ++j) acc[i][j] = (f32x4)0.f;
  }

  const int nk = K >> 5;
  // prologue: stage K-tiles 0 (buf0) and 1 (buf1)
  gld16(gA0, &smem[lw]);
  gld16(gA1, &smem[4096 + lw]);
  gld16(gB0, &smem[8192 + lw]);
  gld16(gB1, &smem[12288 + lw]);
  gld16(gA0 + 32, &smem[16384 + lw]);
  gld16(gA1 + 32, &smem[16384 + 4096 + lw]);
  gld16(gB0 + 32, &smem[16384 + 8192 + lw]);
  gld16(gB1 + 32, &smem[16384 + 12288 + lw]);

  int cur = 0;
  for (int t = 0; t < nk; ++t) {
    // tile t's 4 loads complete; tile t+1's 4 may remain in flight
    if (t < nk - 1)
      asm volatile("s_waitcnt vmcnt(4)" ::: "memory");
    else
      asm volatile("s_waitcnt vmcnt(0)" ::: "memory");
    __builtin_amdgcn_s_barrier();
    __builtin_amdgcn_sched_barrier(0);

    const unsigned short* sA = smem + cur * 16384;
    const unsigned short* sB = sA + 8192;
    int nxt = cur + 2;
    if (nxt >= 3) nxt -= 3;
    unsigned short* nbase = smem + nxt * 16384;
    const bool more = (t + 2) < nk;
    const int kn = (t + 2) << 5;

    // ---- phase 0: B frags + A frags 0,1; issue next-next A ----
    f16x8 b0 = *(const f16x8*)&sB[boff];
    f16x8 b1 = *(const f16x8*)&sB[boff + 512];
    f16x8 b2 = *(const f16x8*)&sB[boff + 1024];
    f16x8 b3 = *(const f16x8*)&sB[boff + 1536];
    {
      f16x8 a0 = *(const f16x8*)&sA[aoff];
      f16x8 a1 = *(const f16x8*)&sA[aoff + 512];
      if (more) {
        gld16(gA0 + kn, nbase + lw);
        gld16(gA1 + kn, nbase + 4096 + lw);
      }
      __builtin_amdgcn_sched_barrier(0);
      __builtin_amdgcn_s_setprio(1);
      acc[0][0] = MFMA16(a0, b0, acc[0][0]);
      acc[0][1] = MFMA16(a0, b1, acc[0][1]);
      acc[0][2] = MFMA16(a0, b2, acc[0][2]);
      acc[0][3] = MFMA16(a0, b3, acc[0][3]);
      acc[1][0] = MFMA16(a1, b0, acc[1][0]);
      acc[1][1] = MFMA16(a1, b1, acc[1][1]);
      acc[1][2] = MFMA16(a1, b2, acc[1][2]);
      acc[1][3] = MFMA16(a1, b3, acc[1][3]);
      __builtin_amdgcn_s_setprio(0);
      __builtin_amdgcn_sched_barrier(0);
    }
    // ---- phase 1: A frags 2,3; issue next-next B ----
    {
      f16x8 a0 = *(const f16x8*)&sA[aoff + 1024];
      f16x8 a1 = *(const f16x8*)&sA[aoff + 1536];
      if (more) {
        gld16(gB0 + kn, nbase + 8192 + lw);
        gld16(gB1 + kn, nbase + 12288 + lw);
      }
      __builtin_amdgcn_sched_barrier(0);
      __builtin_amdgcn_s_setprio(1);
      acc[2][0] = MFMA16(a0, b0, acc[2][0]);
      acc[2][1] = MFMA16(a0, b1, acc[2][1]);
      acc[2][2] = MFMA16(a0, b2, acc[2][2]);
      acc[2][3] = MFMA16(a0, b3, acc[2][3]);
      acc[3][0] = MFMA16(a1, b0, acc[3][0]);
      acc[3][1] = MFMA16(a1, b1, acc[3][1]);
      acc[3][2] = MFMA16(a1, b2, acc[3][2]);
      acc[3][3] = MFMA16(a1, b3, acc[3][3]);
      __builtin_amdgcn_s_setprio(0);
      __builtin_amdgcn_sched_barrier(0);
    }
    // ---- phase 2: A frags 4,5 ----
    {
      f16x8 a0 = *(const f16x8*)&sA[aoff + 2048];
      f16x8 a1 = *(const f16x8*)&sA[aoff + 2560];
      __builtin_amdgcn_sched_barrier(0);
      __builtin_amdgcn_s_setprio(1);
      acc[4][0] = MFMA16(a0, b0, acc[4][0]);
      acc[4][1] = MFMA16(a0, b1, acc[4][1]);
      acc[4][2] = MFMA16(a0, b2, acc[4][2]);
      acc[4][3] = MFMA16(a0, b3, acc[4][3]);
      acc[5][0] = MFMA16(a1, b0, acc[5][0]);
      acc[5][1] = MFMA16(a1, b1, acc[5][1]);
      acc[5][2] = MFMA16(a1, b2, acc[5][2]);
      acc[5][3] = MFMA16(a1, b3, acc[5][3]);
      __builtin_amdgcn_s_setprio(0);
      __builtin_amdgcn_sched_barrier(0);
    }
    // ---- phase 3: A frags 6,7 ----
    {
      f16x8 a0 = *(const f16x8*)&sA[aoff + 3072];
      f16x8 a1 = *(const f16x8*)&sA[aoff + 3584];
      __builtin_amdgcn_sched_barrier(0);
      __builtin_amdgcn_s_setprio(1);
      acc[6][0] = MFMA16(a0, b0, acc[6][0]);
      acc[6][1] = MFMA16(a0, b1, acc[6][1]);
      acc[6][2] = MFMA16(a0, b2, acc[6][2]);
      acc[6][3] = MFMA16(a0, b3, acc[6][3]);
      acc[7][0] = MFMA16(a1, b0, acc[7][0]);
      acc[7][1] = MFMA16(a1, b1, acc[7][1]);
      acc[7][2] = MFMA16(a1, b2, acc[7][2]);
      acc[7][3] = MFMA16(a1, b3, acc[7][3]);
      __builtin_amdgcn_s_setprio(0);
      __builtin_amdgcn_sched_barrier(0);
    }
    cur += 1;
    if (cur >= 3) cur -= 3;
  }

  // epilogue; frag: D[row=fc*4+i][col=fr]
  if constexpr (EPI == 5) {
    unsigned short* Ch = (unsigned short*)Cv;
    const int Nh = N >> 1;
#pragma unroll
    for (int mi = 0; mi < 8; ++mi) {
#pragma unroll
      for (int p = 0; p < 2; ++p) {
        const int hcol = (((n0 + wc * 64) >> 5) + p) * 16 + fr;
        const int mb = m0 + wr * 128 + mi * 16 + fc * 4;
#pragma unroll
        for (int i = 0; i < 4; ++i) {
          const int m = mb + i;
          float v1 = acc[mi][2 * p][i];
          float v3 = acc[mi][2 * p + 1][i];
          float y = v1 / (1.f + __expf(-v1)) * v3;
          Ch[(size_t)m * Nh + hcol] = f2h(y);
        }
      }
    }
  } else {
    unsigned short* Ch = (unsigned short*)Cv;
#pragma unroll
    for (int mi = 0; mi < 8; ++mi) {
#pragma unroll
      for (int ni = 0; ni < 4; ++ni) {
        const int n = n0 + wc * 64 + ni * 16 + fr;
        const int mb = m0 + wr * 128 + mi * 16 + fc * 4;
#pragma unroll
        for (int i = 0; i < 4; ++i) {
          const int m = mb + i;
          float v = acc[mi][ni][i];
          if (bias) v += bias[n];
          Ch[(size_t)m * N + n] = f2h(v);
        }
      }
    }
  }
}

// ---------------- host ----------------

extern "C" void kernel_launch(void* const* d_in, const int* in_sizes, int n_in,
                              void* d_out, int out_size, void* d_ws, size_t ws_size,
                              hipStream_t stream) {
  (void)in_sizes; (void)n_in; (void)out_size; (void)ws_size;
  const float* hs = (const float*)d_in[0];
  const float* temb = (const float*)d_in[1];
  const float* rope = (const float*)d_in[2];
  const float* adaw = (const float*)d_in[3];
  const float* adab = (const float*)d_in[4];
  const float* qkvw = (const float*)d_in[5];
  const float* qkvb = (const float*)d_in[6];
  const float* qnw = (const float*)d_in[7];
  const float* knw = (const float*)d_in[8];
  const float* outw = (const float*)d_in[9];
  const float* outb = (const float*)d_in[10];
  const float* gatew = (const float*)d_in[11];
  const float* ew1 = (const float*)d_in[12];
  const float* ew2 = (const float*)d_in[13];
  const float* ew3 = (const float*)d_in[14];
  const float* sw1 = (const float*)d_in[15];
  const float* sw2 = (const float*)d_in[16];
  const float* sw3 = (const float*)d_in[17];
  float* out = (float*)d_out;
  char* ws = (char*)d_ws;

  size_t off = 0;
  auto give = [&](size_t nbytes) {
    size_t r = off;
    off += (nbytes + 255) & ~(size_t)255;
    return r;
  };
  const size_t T = T_TOK, D = DIM;
  size_t o_mod = give(15360 * 4);
  size_t o_ss = give(D * 4);
  size_t o_wd = give(T * 4 * 4);
  size_t o_idx = give(MPAD * 4);
  size_t o_seg = give(8 * 4);
  size_t o_slot = give(T * 2 * 4);
  size_t o_wab = give(T * 2 * 4);
  size_t o_nh = give(T * D * 2);      // nh fp16; later nh2
  size_t o_qkvh = give(T * 7680 * 2); // qkv fp16; region later reused as hmid
  size_t o_qh = give(T * D * 2);
  size_t o_kh = give(T * D * 2);
  size_t o_vt = give(T * D * 2);
  size_t o_obf = give(T * D * 2);
  size_t o_h2 = give(T * D * 4);
  size_t o_yc = give((size_t)MPAD * D * 2);       // compact expert outputs fp16
  size_t o_hmid2 = give(T * SHID_E * 2);          // shared-expert mid
  // fp16 weights
  size_t o_qkvw = give((size_t)7680 * 2560 * 2);
  size_t o_outw = give((size_t)2560 * 2560 * 2);
  size_t o_ewA = give((size_t)4 * 2 * HID_E * 2560 * 2);  // interleaved w1/w3
  size_t o_ew2 = give((size_t)4 * 2560 * HID_E * 2);
  size_t o_swA = give((size_t)2 * SHID_E * 2560 * 2);     // interleaved sw1/sw3
  size_t o_sw2 = give((size_t)2560 * SHID_E * 2);

  float* mod = (float*)(ws + o_mod);
  float* ss = (float*)(ws + o_ss);
  float* wd = (float*)(ws + o_wd);
  int* idxb = (int*)(ws + o_idx);
  int* segp = (int*)(ws + o_seg);
  int* slotAB = (int*)(ws + o_slot);
  float* wAB = (float*)(ws + o_wab);
  unsigned short* nh_h = (unsigned short*)(ws + o_nh);
  unsigned short* qkvh = (unsigned short*)(ws + o_qkvh);
  unsigned short* qh = (unsigned short*)(ws + o_qh);
  unsigned short* kh = (unsigned short*)(ws + o_kh);
  unsigned short* vt = (unsigned short*)(ws + o_vt);
  unsigned short* obf = (unsigned short*)(ws + o_obf);
  float* h2 = (float*)(ws + o_h2);
  unsigned short* yc = (unsigned short*)(ws + o_yc);
  unsigned short* hmid2 = (unsigned short*)(ws + o_hmid2);
  unsigned short* qkvw_h = (unsigned short*)(ws + o_qkvw);
  unsigned short* outw_h = (unsigned short*)(ws + o_outw);
  unsigned short* ewA_h = (unsigned short*)(ws + o_ewA);
  unsigned short* ew2_h = (unsigned short*)(ws + o_ew2);
  unsigned short* swA_h = (unsigned short*)(ws + o_swA);
  unsigned short* sw2_h = (unsigned short*)(ws + o_sw2);
  unsigned short* nh2 = nh_h;
  // hmid (MPAD x 6912 fp16 = 70.8 MB) aliases qkvh..obf (73.4 MB), dead after out-proj
  unsigned short* hmid = qkvh;

  // 0) weight conversion f32 -> fp16 (fused) + w1/w3 interleave (fused)
  cvt_all4<<<4096, 256, 0, stream>>>(qkvw, qkvw_h, 7680L * 2560 / 8,
                                     outw, outw_h, 2560L * 2560 / 8,
                                     ew2, ew2_h, 4L * 2560 * HID_E / 8,
                                     sw2, sw2_h, 2560L * SHID_E / 8);
  cvt_pair_all<<<4 * 2 * HID_E + 2 * SHID_E, 256, 0, stream>>>(ew1, ew3, sw1, sw3,
                                                               ewA_h, swA_h);
  // 1) adaLN modulation
  silu_k<<<10, 256, 0, stream>>>(temb, ss);
  adaln_gemv<<<3840, 256, 0, stream>>>(ss, adaw, adab, mod);
  // 2) LN1 + modulate (fp16)
  ln_mod<<<T, 256, 0, stream>>>(hs, mod, mod + D, nh_h);
  // 3) qkv GEMM -> fp16 (256-tile)
  gemm256<4, 0><<<240, 512, 0, stream>>>(nh_h, qkvw_h, qkvb, qkvh,
                                         nullptr, nullptr, 2048, 7680, 2560);
  // 4) RMSNorm + RoPE
  rmsrope<<<T, 256, 0, stream>>>(qkvh, qnw, knw, rope, qh, kh);
  // 5) V transpose
  transpose_v<<<dim3(80, 64), dim3(32, 8), 0, stream>>>(qkvh, vt);
  // 6) MFMA flash attention
  fattn<<<dim3(32, 20), 256, 0, stream>>>(qh, kh, vt, obf);
  // 7) out proj + gate_msa residual -> h2 f32
  gemm128<1, 0><<<16 * 20, 256, 0, stream>>>(obf, outw_h, outb, h2,
                                             mod + 2 * D, hs, nullptr, nullptr,
                                             nullptr, nullptr, nullptr, 2048, 2560, 2560);
  // 8) LN2 + modulate + routing, then concatenated 256-padded compaction
  ln2_route<<<T, 256, 0, stream>>>(h2, mod + 3 * D, mod + 4 * D, gatew, nh2, wd);
  route_compact<<<1, 256, 0, stream>>>(wd, idxb, segp, slotAB, wAB);
  // 9) MoE experts: fused w1w3+swiglu 256-tile GEMM + w2 256-tile GEMM
  gemm256<5, 1><<<20 * 54, 512, 0, stream>>>(nh2, ewA_h, nullptr, hmid,
                                             idxb, segp, MPAD, 2 * HID_E, 2560);
  gemm256<4, 2><<<20 * 10, 512, 0, stream>>>(hmid, ew2_h, nullptr, yc,
                                             nullptr, segp, MPAD, 2560, 6912);
  // 10) shared expert (256-tile fused w1w3+swiglu) + final combine w/ yc gather
  gemm256<5, 0><<<8 * 28, 512, 0, stream>>>(nh2, swA_h, nullptr, hmid2,
                                            nullptr, nullptr, 2048, 2 * SHID_E, 2560);
  gemm128<6, 0><<<16 * 20, 256, 0, stream>>>(hmid2, sw2_h, nullptr, out,
                                             mod + 5 * D, h2, nullptr, nullptr,
                                             slotAB, wAB, yc, 2048, 2560, 3584);
}

// Round 14
// 1343.421 us; speedup vs baseline: 1.1360x; 1.0322x over previous
//
#include <hip/hip_runtime.h>

#define DIM 2560
#define T_TOK 2048
#define NHEADS 20
#define HD 128
#define HID_E 6912
#define SHID_E 3584
#define MPAD 5120  // concat rows, segments padded to 256 (max 4096+4*255 <= 5120)

typedef _Float16 f16x8 __attribute__((ext_vector_type(8)));
typedef float f32x4 __attribute__((ext_vector_type(4)));
typedef unsigned short u16x8 __attribute__((ext_vector_type(8)));

#define MFMA16(a, b, c) __builtin_amdgcn_mfma_f32_16x16x32_f16((a), (b), (c), 0, 0, 0)

__device__ inline unsigned short f2h(float f) {
  return __builtin_bit_cast(unsigned short, (_Float16)f);
}
__device__ inline float h2f(unsigned short u) {
  return (float)__builtin_bit_cast(_Float16, u);
}
__device__ inline float wave_sum(float v) {
#pragma unroll
  for (int off = 32; off > 0; off >>= 1) v += __shfl_down(v, off, 64);
  return v;
}
// async global->LDS, 16B per lane; LDS dest = wave-uniform base + lane*16
__device__ inline void gld16(const void* g, void* l) {
  __builtin_amdgcn_global_load_lds((const __attribute__((address_space(1))) void*)g,
                                   (__attribute__((address_space(3))) void*)l, 16, 0, 0);
}

// ---------------- tiny kernels ----------------

__global__ __launch_bounds__(256) void silu_k(const float* __restrict__ t,
                                              float* __restrict__ ss) {
  int i = blockIdx.x * 256 + threadIdx.x;
  if (i < DIM) {
    float v = t[i];
    ss[i] = v / (1.f + expf(-v));
  }
}

// fused f32->fp16 conversion over 2 segments (n in groups of 8)
__global__ __launch_bounds__(256) void cvt_all2(
    const float* __restrict__ s0, unsigned short* __restrict__ d0, long n0,
    const float* __restrict__ s1, unsigned short* __restrict__ d1, long n1) {
  const long stride = (long)gridDim.x * 256;
  const long tot = n0 + n1;
  for (long i = (long)blockIdx.x * 256 + threadIdx.x; i < tot; i += stride) {
    const float* s;
    unsigned short* d;
    long j;
    if (i < n0) { s = s0; d = d0; j = i; }
    else { s = s1; d = d1; j = i - n0; }
    float4 a = *(const float4*)(s + j * 8);
    float4 b = *(const float4*)(s + j * 8 + 4);
    u16x8 u;
    u[0] = f2h(a.x); u[1] = f2h(a.y); u[2] = f2h(a.z); u[3] = f2h(a.w);
    u[4] = f2h(b.x); u[5] = f2h(b.y); u[6] = f2h(b.z); u[7] = f2h(b.w);
    *(u16x8*)&d[j * 8] = u;
  }
}

// mod[j] = dot(silu(temb), adaln_w[j]) + adaln_b[j]; one wave per output
__global__ __launch_bounds__(256) void adaln_gemv(const float* __restrict__ ss,
                                                  const float* __restrict__ W,
                                                  const float* __restrict__ bias,
                                                  float* __restrict__ mod) {
  const int lane = threadIdx.x & 63;
  const int j = blockIdx.x * 4 + (threadIdx.x >> 6);
  const float* wr = W + (size_t)j * DIM;
  float p = 0.f;
  for (int i = lane; i < 640; i += 64) {
    float4 w = *(const float4*)(wr + i * 4);
    float4 x = *(const float4*)(ss + i * 4);
    p += w.x * x.x + w.y * x.y + w.z * x.z + w.w * x.w;
  }
  p = wave_sum(p);
  if (lane == 0) mod[j] = p + bias[j];
}

// LN (no affine) then *(1+scale)+shift, write fp16. One block per row.
__global__ __launch_bounds__(256) void ln_mod(const float* __restrict__ x,
                                              const float* __restrict__ shift,
                                              const float* __restrict__ scale,
                                              unsigned short* __restrict__ outp) {
  __shared__ float rbuf[8];
  const int t = blockIdx.x, tid = threadIdx.x, lane = tid & 63, wid = tid >> 6;
  const float* xr = x + (size_t)t * DIM;
  float s = 0.f, sq = 0.f;
  for (int i = tid; i < 640; i += 256) {
    float4 v = *(const float4*)(xr + i * 4);
    s += v.x + v.y + v.z + v.w;
    sq += v.x * v.x + v.y * v.y + v.z * v.z + v.w * v.w;
  }
  s = wave_sum(s);
  sq = wave_sum(sq);
  if (lane == 0) {
    rbuf[wid] = s;
    rbuf[4 + wid] = sq;
  }
  __syncthreads();
  float S = rbuf[0] + rbuf[1] + rbuf[2] + rbuf[3];
  float SQ = rbuf[4] + rbuf[5] + rbuf[6] + rbuf[7];
  float mean = S * (1.f / DIM);
  float rs = rsqrtf(SQ * (1.f / DIM) - mean * mean + 1e-6f);
  for (int i = tid; i < 640; i += 256) {
    float4 v = *(const float4*)(xr + i * 4);
    float4 sc4 = *(const float4*)(scale + i * 4);
    float4 sh4 = *(const float4*)(shift + i * 4);
    ushort4 u;
    u.x = f2h((v.x - mean) * rs * (1.f + sc4.x) + sh4.x);
    u.y = f2h((v.y - mean) * rs * (1.f + sc4.y) + sh4.y);
    u.z = f2h((v.z - mean) * rs * (1.f + sc4.z) + sh4.z);
    u.w = f2h((v.w - mean) * rs * (1.f + sc4.w) + sh4.w);
    *(ushort4*)&outp[(size_t)t * DIM + i * 4] = u;
  }
}

// RMSNorm(q),(k) over full 2560 + weight + RoPE -> qh (scaled by 1/sqrt(128)), kh
__global__ __launch_bounds__(256) void rmsrope(const unsigned short* __restrict__ qkv,
                                               const float* __restrict__ qn,
                                               const float* __restrict__ kn,
                                               const float* __restrict__ rope,
                                               unsigned short* __restrict__ qh,
                                               unsigned short* __restrict__ kh) {
  __shared__ float rbuf[8];
  const int t = blockIdx.x, tid = threadIdx.x, lane = tid & 63, wid = tid >> 6;
  const unsigned short* row = qkv + (size_t)t * 7680;
  float sq = 0.f, sk = 0.f;
  for (int i = tid; i < 320; i += 256) {
    f16x8 qv = *(const f16x8*)(row + i * 8);
    f16x8 kv = *(const f16x8*)(row + DIM + i * 8);
#pragma unroll
    for (int j = 0; j < 8; ++j) {
      float q = (float)qv[j], k = (float)kv[j];
      sq += q * q;
      sk += k * k;
    }
  }
  sq = wave_sum(sq);
  sk = wave_sum(sk);
  if (lane == 0) {
    rbuf[wid] = sq;
    rbuf[4 + wid] = sk;
  }
  __syncthreads();
  float SQ = rbuf[0] + rbuf[1] + rbuf[2] + rbuf[3];
  float SK = rbuf[4] + rbuf[5] + rbuf[6] + rbuf[7];
  float rq = rsqrtf(SQ * (1.f / DIM) + 1e-6f) * 0.08838834764831845f;
  float rk = rsqrtf(SK * (1.f / DIM) + 1e-6f);
  for (int pp = tid; pp < 1280; pp += 256) {
    int c = pp * 2;
    float qe = h2f(row[c]) * rq * qn[c], qo = h2f(row[c + 1]) * rq * qn[c + 1];
    float ke = h2f(row[DIM + c]) * rk * kn[c], ko = h2f(row[DIM + c + 1]) * rk * kn[c + 1];
    float4 rr = *(const float4*)(rope + (size_t)t * 256 + (pp & 63) * 4);
    unsigned qp = (unsigned)f2h(rr.x * qe + rr.y * qo) |
                  ((unsigned)f2h(rr.z * qe + rr.w * qo) << 16);
    unsigned kp = (unsigned)f2h(rr.x * ke + rr.y * ko) |
                  ((unsigned)f2h(rr.z * ke + rr.w * ko) << 16);
    *(unsigned*)&qh[(size_t)t * DIM + c] = qp;
    *(unsigned*)&kh[(size_t)t * DIM + c] = kp;
  }
}

// V part of qkv (fp16 [2048][7680] at col 5120) -> vt fp16 [2560][2048]
__global__ void transpose_v(const unsigned short* __restrict__ in,
                            unsigned short* __restrict__ outp) {
  __shared__ unsigned short tile[32][33];
  const int bx = blockIdx.x * 32;  // channel
  const int by = blockIdx.y * 32;  // token
  const int tx = threadIdx.x, ty = threadIdx.y;
  for (int j = ty; j < 32; j += 8)
    tile[j][tx] = in[(size_t)(by + j) * 7680 + 5120 + bx + tx];
  __syncthreads();
  for (int j = ty; j < 32; j += 8)
    outp[(size_t)(bx + j) * T_TOK + by + tx] = tile[tx][j];
}

// ---------------- MFMA flash attention (single 64-q tile per block) ----------------
__global__ __launch_bounds__(256) void fattn(const unsigned short* __restrict__ qh,
                                             const unsigned short* __restrict__ kh,
                                             const unsigned short* __restrict__ vt,
                                             unsigned short* __restrict__ obuf) {
  __shared__ unsigned short sK[64 * 128];  // [k][d], slot = c ^ (r&15)
  __shared__ unsigned short sV[128 * 64];  // [d][k], slot = c ^ (r&7)
  __shared__ unsigned short sP[64 * 64];   // [q][k], slot = c ^ (r&7)
  __shared__ float sRedM[4][64];
  __shared__ float sRedL[4][64];
  __shared__ float sM[64];
  __shared__ float sL[64];
  const int tid = threadIdx.x, lane = tid & 63, wv = tid >> 6;
  const int g = lane >> 4, fr = lane & 15;
  const int h = blockIdx.y;
  const int q0 = blockIdx.x * 64;

  {
    const int r = tid >> 2, qt = tid & 3;
    const unsigned short* gp = qh + (size_t)(q0 + r) * DIM + h * HD + qt * 32;
    uint4 v0 = ((const uint4*)gp)[0];
    uint4 v1 = ((const uint4*)gp)[1];
    uint4 v2 = ((const uint4*)gp)[2];
    uint4 v3 = ((const uint4*)gp)[3];
    unsigned short* dst = &sK[r * 128];
    const int cb = qt * 4, rs = r & 15;
    *(uint4*)&dst[((cb + 0) ^ rs) * 8] = v0;
    *(uint4*)&dst[((cb + 1) ^ rs) * 8] = v1;
    *(uint4*)&dst[((cb + 2) ^ rs) * 8] = v2;
    *(uint4*)&dst[((cb + 3) ^ rs) * 8] = v3;
  }
  __syncthreads();
  f16x8 qfrag[4][4];
#pragma unroll
  for (int ni = 0; ni < 4; ++ni) {
#pragma unroll
    for (int kt = 0; kt < 4; ++kt) {
      int r = ni * 16 + fr;
      qfrag[ni][kt] = *(const f16x8*)&sK[r * 128 + (((kt * 4 + g) ^ (r & 15)) << 3)];
    }
  }
  __syncthreads();

  f32x4 acco[4][2];
  f32x4 mprev[4];
  float mrun[4], lrun[4];
#pragma unroll
  for (int i = 0; i < 4; ++i) {
    acco[i][0] = (f32x4)0.f;
    acco[i][1] = (f32x4)0.f;
    mprev[i] = (f32x4)(-1e30f);
    mrun[i] = -1e30f;
    lrun[i] = 0.f;
  }

  for (int kt0 = 0; kt0 < T_TOK; kt0 += 64) {
    {
      const int r = tid >> 2, qt = tid & 3;
      const unsigned short* gp = kh + (size_t)(kt0 + r) * DIM + h * HD + qt * 32;
      uint4 v0 = ((const uint4*)gp)[0];
      uint4 v1 = ((const uint4*)gp)[1];
      uint4 v2 = ((const uint4*)gp)[2];
      uint4 v3 = ((const uint4*)gp)[3];
      unsigned short* dst = &sK[r * 128];
      const int cb = qt * 4, rs = r & 15;
      *(uint4*)&dst[((cb + 0) ^ rs) * 8] = v0;
      *(uint4*)&dst[((cb + 1) ^ rs) * 8] = v1;
      *(uint4*)&dst[((cb + 2) ^ rs) * 8] = v2;
      *(uint4*)&dst[((cb + 3) ^ rs) * 8] = v3;
      const int rv = tid >> 1, hf = tid & 1;
      const unsigned short* gv = vt + (size_t)(h * HD + rv) * T_TOK + kt0 + hf * 32;
      uint4 w0 = ((const uint4*)gv)[0];
      uint4 w1 = ((const uint4*)gv)[1];
      uint4 w2 = ((const uint4*)gv)[2];
      uint4 w3 = ((const uint4*)gv)[3];
      unsigned short* dv = &sV[rv * 64];
      const int cv = hf * 4, rvs = rv & 7;
      *(uint4*)&dv[((cv + 0) ^ rvs) * 8] = w0;
      *(uint4*)&dv[((cv + 1) ^ rvs) * 8] = w1;
      *(uint4*)&dv[((cv + 2) ^ rvs) * 8] = w2;
      *(uint4*)&dv[((cv + 3) ^ rvs) * 8] = w3;
    }
    __syncthreads();  // B0

    f32x4 accs[4] = {(f32x4)0.f, (f32x4)0.f, (f32x4)0.f, (f32x4)0.f};
#pragma unroll
    for (int kt = 0; kt < 4; ++kt) {
      int r = wv * 16 + fr;
      f16x8 ak = *(const f16x8*)&sK[r * 128 + (((kt * 4 + g) ^ (r & 15)) << 3)];
#pragma unroll
      for (int ni = 0; ni < 4; ++ni) accs[ni] = MFMA16(ak, qfrag[ni][kt], accs[ni]);
    }

    float pm[4];
#pragma unroll
    for (int ni = 0; ni < 4; ++ni) {
      float m = fmaxf(fmaxf(accs[ni][0], accs[ni][1]), fmaxf(accs[ni][2], accs[ni][3]));
      m = fmaxf(m, __shfl_xor(m, 16));
      m = fmaxf(m, __shfl_xor(m, 32));
      pm[ni] = m;
    }
    if (g == 0) {
#pragma unroll
      for (int ni = 0; ni < 4; ++ni) sRedM[wv][ni * 16 + fr] = pm[ni];
    }
    __syncthreads();  // B1
    float mnew[4];
#pragma unroll
    for (int ni = 0; ni < 4; ++ni) {
      int q = ni * 16 + fr;
      float mt = fmaxf(fmaxf(sRedM[0][q], sRedM[1][q]), fmaxf(sRedM[2][q], sRedM[3][q]));
      mnew[ni] = fmaxf(mrun[ni], mt);
    }
    float lsum[4];
#pragma unroll
    for (int ni = 0; ni < 4; ++ni) {
      float l0 = 0.f;
#pragma unroll
      for (int i = 0; i < 4; ++i) {
        float p = __expf(accs[ni][i] - mnew[ni]);
        accs[ni][i] = p;
        l0 += p;
      }
      l0 += __shfl_xor(l0, 16);
      l0 += __shfl_xor(l0, 32);
      lsum[ni] = l0;
    }
    if (g == 0) {
#pragma unroll
      for (int ni = 0; ni < 4; ++ni) sRedL[wv][ni * 16 + fr] = lsum[ni];
      if (wv == 0) {
#pragma unroll
        for (int ni = 0; ni < 4; ++ni) sM[ni * 16 + fr] = mnew[ni];
      }
    }
#pragma unroll
    for (int ni = 0; ni < 4; ++ni) {
      int q = ni * 16 + fr;
      unsigned p01 = (unsigned)f2h(accs[ni][0]) | ((unsigned)f2h(accs[ni][1]) << 16);
      unsigned p23 = (unsigned)f2h(accs[ni][2]) | ((unsigned)f2h(accs[ni][3]) << 16);
      uint2 pk;
      pk.x = p01;
      pk.y = p23;
      *(uint2*)&sP[q * 64 + ((((wv << 1) | (g >> 1)) ^ (q & 7)) << 3) + ((g & 1) << 2)] = pk;
    }
    __syncthreads();  // B2
#pragma unroll
    for (int ni = 0; ni < 4; ++ni) {
      int q = ni * 16 + fr;
      float lt = sRedL[0][q] + sRedL[1][q] + sRedL[2][q] + sRedL[3][q];
      lrun[ni] = lrun[ni] * __expf(mrun[ni] - mnew[ni]) + lt;
      mrun[ni] = mnew[ni];
    }

#pragma unroll
    for (int mi = 0; mi < 4; ++mi) {
      f32x4 mn = *(const f32x4*)&sM[mi * 16 + g * 4];
      f32x4 sc;
#pragma unroll
      for (int i = 0; i < 4; ++i) sc[i] = __expf(mprev[mi][i] - mn[i]);
      acco[mi][0] *= sc;
      acco[mi][1] *= sc;
      mprev[mi] = mn;
    }
#pragma unroll
    for (int ktp = 0; ktp < 2; ++ktp) {
      f16x8 bv[2];
#pragma unroll
      for (int nd = 0; nd < 2; ++nd) {
        int r = wv * 32 + nd * 16 + fr;
        bv[nd] = *(const f16x8*)&sV[r * 64 + (((ktp * 4 + g) ^ (r & 7)) << 3)];
      }
#pragma unroll
      for (int mi = 0; mi < 4; ++mi) {
        int r = mi * 16 + fr;
        f16x8 ap = *(const f16x8*)&sP[r * 64 + (((ktp * 4 + g) ^ (r & 7)) << 3)];
        acco[mi][0] = MFMA16(ap, bv[0], acco[mi][0]);
        acco[mi][1] = MFMA16(ap, bv[1], acco[mi][1]);
      }
    }
    __syncthreads();  // B3
  }

  if (wv == 0 && g == 0) {
#pragma unroll
    for (int ni = 0; ni < 4; ++ni) sL[ni * 16 + fr] = 1.f / lrun[ni];
  }
  __syncthreads();
#pragma unroll
  for (int mi = 0; mi < 4; ++mi) {
    f32x4 li = *(const f32x4*)&sL[mi * 16 + g * 4];
#pragma unroll
    for (int nd = 0; nd < 2; ++nd) {
#pragma unroll
      for (int i = 0; i < 4; ++i) {
        float o = acco[mi][nd][i] * li[i];
        obuf[(size_t)(q0 + mi * 16 + g * 4 + i) * DIM + h * HD + wv * 32 + nd * 16 + fr] =
            f2h(o);
      }
    }
  }
}

// LN2 + modulate -> nh2 fp16, plus f32 routing (softmax over 4, top-2, unnormalized)
__global__ __launch_bounds__(256) void ln2_route(const float* __restrict__ x,
                                                 const float* __restrict__ shift,
                                                 const float* __restrict__ scale,
                                                 const float* __restrict__ gw,
                                                 unsigned short* __restrict__ nh2,
                                                 float* __restrict__ wd) {
  __shared__ float rbuf[8];
  __shared__ float gbuf[4][4];
  const int t = blockIdx.x, tid = threadIdx.x, lane = tid & 63, wid = tid >> 6;
  const float* xr = x + (size_t)t * DIM;
  float s = 0.f, sq = 0.f;
  for (int i = tid; i < 640; i += 256) {
    float4 v = *(const float4*)(xr + i * 4);
    s += v.x + v.y + v.z + v.w;
    sq += v.x * v.x + v.y * v.y + v.z * v.z + v.w * v.w;
  }
  s = wave_sum(s);
  sq = wave_sum(sq);
  if (lane == 0) {
    rbuf[wid] = s;
    rbuf[4 + wid] = sq;
  }
  __syncthreads();
  float S = rbuf[0] + rbuf[1] + rbuf[2] + rbuf[3];
  float SQ = rbuf[4] + rbuf[5] + rbuf[6] + rbuf[7];
  float mean = S * (1.f / DIM);
  float rs = rsqrtf(SQ * (1.f / DIM) - mean * mean + 1e-6f);
  float g0 = 0.f, g1 = 0.f, g2 = 0.f, g3 = 0.f;
  for (int i = tid; i < 640; i += 256) {
    float4 v = *(const float4*)(xr + i * 4);
    float4 sc4 = *(const float4*)(scale + i * 4);
    float4 sh4 = *(const float4*)(shift + i * 4);
    float y0 = (v.x - mean) * rs * (1.f + sc4.x) + sh4.x;
    float y1 = (v.y - mean) * rs * (1.f + sc4.y) + sh4.y;
    float y2 = (v.z - mean) * rs * (1.f + sc4.z) + sh4.z;
    float y3 = (v.w - mean) * rs * (1.f + sc4.w) + sh4.w;
    ushort4 u;
    u.x = f2h(y0); u.y = f2h(y1); u.z = f2h(y2); u.w = f2h(y3);
    *(ushort4*)&nh2[(size_t)t * DIM + i * 4] = u;
    float4 w0 = *(const float4*)(gw + i * 4);
    float4 w1 = *(const float4*)(gw + DIM + i * 4);
    float4 w2 = *(const float4*)(gw + 2 * DIM + i * 4);
    float4 w3 = *(const float4*)(gw + 3 * DIM + i * 4);
    g0 += y0 * w0.x + y1 * w0.y + y2 * w0.z + y3 * w0.w;
    g1 += y0 * w1.x + y1 * w1.y + y2 * w1.z + y3 * w1.w;
    g2 += y0 * w2.x + y1 * w2.y + y2 * w2.z + y3 * w2.w;
    g3 += y0 * w3.x + y1 * w3.y + y2 * w3.z + y3 * w3.w;
  }
  g0 = wave_sum(g0);
  g1 = wave_sum(g1);
  g2 = wave_sum(g2);
  g3 = wave_sum(g3);
  if (lane == 0) {
    gbuf[wid][0] = g0; gbuf[wid][1] = g1; gbuf[wid][2] = g2; gbuf[wid][3] = g3;
  }
  __syncthreads();
  if (tid == 0) {
    float l[4];
#pragma unroll
    for (int e = 0; e < 4; ++e) l[e] = gbuf[0][e] + gbuf[1][e] + gbuf[2][e] + gbuf[3][e];
    float mx = fmaxf(fmaxf(l[0], l[1]), fmaxf(l[2], l[3]));
    float ex[4], sum = 0.f;
#pragma unroll
    for (int e = 0; e < 4; ++e) { ex[e] = expf(l[e] - mx); sum += ex[e]; }
    float p[4];
#pragma unroll
    for (int e = 0; e < 4; ++e) p[e] = ex[e] / sum;
    int i1 = 0;
    for (int e = 1; e < 4; ++e)
      if (p[e] > p[i1]) i1 = e;
    int i2 = -1;
    for (int e = 0; e < 4; ++e) {
      if (e == i1) continue;
      if (i2 < 0 || p[e] > p[i2]) i2 = e;
    }
    float w[4] = {0.f, 0.f, 0.f, 0.f};
    w[i1] = p[i1];
    w[i2] = p[i2];
    *(float4*)&wd[(size_t)t * 4] = make_float4(w[0], w[1], w[2], w[3]);
  }
}

// Concatenated padded top-2 compaction. One block, 256 threads, 8 tokens each.
// Segments padded to 256 (for the 256-tile GEMM). idx pad rows point at token 0.
__global__ __launch_bounds__(256) void route_compact(const float* __restrict__ wd,
                                                     int* __restrict__ idx_all,
                                                     int* __restrict__ seg,
                                                     int* __restrict__ slotAB,
                                                     float* __restrict__ wAB) {
  __shared__ unsigned short c[256][4];
  __shared__ int offs[256][4];
  __shared__ int segs[5];
  const int t = threadIdx.x;
  for (int i = t; i < MPAD; i += 256) idx_all[i] = 0;
  unsigned char sel[8];
  float wv4[8][4];
  unsigned short lc[4] = {0, 0, 0, 0};
#pragma unroll
  for (int k = 0; k < 8; ++k) {
    int tok = t * 8 + k;
    float4 w = *(const float4*)&wd[(size_t)tok * 4];
    wv4[k][0] = w.x; wv4[k][1] = w.y; wv4[k][2] = w.z; wv4[k][3] = w.w;
    unsigned m = 0;
    if (w.x != 0.f) { m |= 1; lc[0]++; }
    if (w.y != 0.f) { m |= 2; lc[1]++; }
    if (w.z != 0.f) { m |= 4; lc[2]++; }
    if (w.w != 0.f) { m |= 8; lc[3]++; }
    sel[k] = (unsigned char)m;
  }
#pragma unroll
  for (int e = 0; e < 4; ++e) c[t][e] = lc[e];
  __syncthreads();
  if (t == 0) {
    int run[4] = {0, 0, 0, 0};
    for (int i = 0; i < 256; ++i) {
#pragma unroll
      for (int e = 0; e < 4; ++e) {
        offs[i][e] = run[e];
        run[e] += c[i][e];
      }
    }
    int s = 0;
    segs[0] = 0;
#pragma unroll
    for (int e = 0; e < 4; ++e) {
      s += (run[e] + 255) & ~255;
      segs[e + 1] = s;
    }
#pragma unroll
    for (int e = 0; e < 5; ++e) seg[e] = segs[e];
  }
  __syncthreads();
  int o[4];
#pragma unroll
  for (int e = 0; e < 4; ++e) o[e] = segs[e] + offs[t][e];
#pragma unroll
  for (int k = 0; k < 8; ++k) {
    int tok = t * 8 + k;
    unsigned m = sel[k];
    int sl[2] = {0, 0};
    float sw[2] = {0.f, 0.f};
    int ns = 0;
#pragma unroll
    for (int e = 0; e < 4; ++e) {
      if ((m >> e) & 1) {
        if (ns < 2) { sl[ns] = o[e]; sw[ns] = wv4[k][e]; }
        idx_all[o[e]++] = tok;
        ns++;
      }
    }
    if (ns == 1) { sl[1] = sl[0]; sw[1] = 0.f; }
    slotAB[tok * 2] = sl[0];
    slotAB[tok * 2 + 1] = sl[1];
    wAB[tok * 2] = sw[0];
    wAB[tok * 2 + 1] = sw[1];
  }
}

// ---------------- gemm128: kept for out-proj / final (epilogue-heavy) ----------------
// EPI: 1 f32 aux0[n]*(v+bias)+aux1 | 4 fp16(+bias) |
//      6 final: aux0[n]*(v + wA*yc[slA]+wB*yc[slB]) + aux1
template <int EPI, int MODE>
__global__ __launch_bounds__(256) void gemm128(
    const unsigned short* __restrict__ A, const unsigned short* __restrict__ B,
    const float* __restrict__ bias, void* __restrict__ Cv,
    const float* __restrict__ aux0, const float* __restrict__ aux1,
    const int* __restrict__ idx, const int* __restrict__ seg,
    const int* __restrict__ slotAB, const float* __restrict__ wAB,
    const unsigned short* __restrict__ yc, int M, int N, int K) {
  __shared__ unsigned short smem[16384];  // 2 bufs x (A 4096 + B 4096)
  const int tid = threadIdx.x;
  const int lane = tid & 63;
  const int wv = tid >> 6;
  const int nwg = gridDim.x;
  const int bid = blockIdx.x;
  const int swzb = (bid & 7) * (nwg >> 3) + (bid >> 3);
  const int gm = M >> 7;
  const int m0 = (swzb % gm) * 128, n0 = (swzb / gm) * 128;
  if (MODE != 0 && m0 >= seg[4]) return;

  const unsigned short* Bp = B;
  if constexpr (MODE != 0) {
    int e = 0;
#pragma unroll
    for (int i = 1; i < 4; ++i)
      if (m0 >= seg[i]) e = i;
    Bp = B + (size_t)e * N * K;
  }

  const int wm = (wv >> 1) * 64, wn = (wv & 1) * 64;
  const int fr = lane & 15, fc = lane >> 4;

  const int rl = lane >> 2, ch = lane & 3;
  const int R1 = wv * 16 + rl;
  const int R2 = 64 + R1;
  const int co1 = ((ch ^ ((R1 >> 1) & 3)) << 3);
  const int co2 = ((ch ^ ((R2 >> 1) & 3)) << 3);
  const size_t ar1 = (size_t)(m0 + R1) * K;
  const size_t ar2 = (size_t)(m0 + R2) * K;
  const unsigned short* gA1 = A + ar1 + co1;
  const unsigned short* gA2 = A + ar2 + co2;
  const unsigned short* gB1 = Bp + (size_t)(n0 + R1) * K + co1;
  const unsigned short* gB2 = Bp + (size_t)(n0 + R2) * K + co2;
  const int lA1 = (wv * 16) * 32, lA2 = (64 + wv * 16) * 32;

  f32x4 acc[4][4];
#pragma unroll
  for (int i = 0; i < 4; ++i) {
#pragma unroll
    for (int j = 0; j < 4; ++j) acc[i][j] = (f32x4)0.f;
  }

  auto STAGE = [&](int buf, int kt) {
    unsigned short* base = smem + buf * 8192;
    gld16(gA1 + kt, base + lA1);
    gld16(gA2 + kt, base + lA2);
    gld16(gB1 + kt, base + 4096 + lA1);
    gld16(gB2 + kt, base + 4096 + lA2);
  };
  auto COMPUTE = [&](int buf) {
    const unsigned short* sA = smem + buf * 8192;
    const unsigned short* sB = sA + 4096;
    f16x8 a[4], b[4];
#pragma unroll
    for (int mi = 0; mi < 4; ++mi) {
      int r = wm + mi * 16 + fr;
      a[mi] = *(const f16x8*)&sA[r * 32 + ((fc ^ ((r >> 1) & 3)) << 3)];
    }
#pragma unroll
    for (int ni = 0; ni < 4; ++ni) {
      int r = wn + ni * 16 + fr;
      b[ni] = *(const f16x8*)&sB[r * 32 + ((fc ^ ((r >> 1) & 3)) << 3)];
    }
#pragma unroll
    for (int mi = 0; mi < 4; ++mi) {
#pragma unroll
      for (int ni = 0; ni < 4; ++ni) acc[mi][ni] = MFMA16(a[mi], b[ni], acc[mi][ni]);
    }
  };

  const int nk = K >> 5;
  STAGE(0, 0);
  __syncthreads();
  int cur = 0;
  for (int t = 1; t < nk; ++t) {
    STAGE(cur ^ 1, t << 5);
    COMPUTE(cur);
    __syncthreads();
    cur ^= 1;
  }
  COMPUTE(cur);

#pragma unroll
  for (int mi = 0; mi < 4; ++mi) {
#pragma unroll
    for (int ni = 0; ni < 4; ++ni) {
      const int n = n0 + wn + ni * 16 + fr;
      const int mb = m0 + wm + mi * 16 + fc * 4;
#pragma unroll
      for (int i = 0; i < 4; ++i) {
        const int m = mb + i;
        float v = acc[mi][ni][i];
        const size_t cidx = (size_t)m * N + n;
        if constexpr (EPI == 1) {
          ((float*)Cv)[cidx] = aux0[n] * (v + bias[n]) + aux1[cidx];
        } else if constexpr (EPI == 4) {
          if (bias) v += bias[n];
          ((unsigned short*)Cv)[cidx] = f2h(v);
        } else if constexpr (EPI == 6) {
          const int sA_ = slotAB[m * 2], sB_ = slotAB[m * 2 + 1];
          const float wA_ = wAB[m * 2], wB_ = wAB[m * 2 + 1];
          float vm = wA_ * h2f(yc[(size_t)sA_ * N + n]) + wB_ * h2f(yc[(size_t)sB_ * N + n]);
          ((float*)Cv)[cidx] = aux0[n] * (v + vm) + aux1[cidx];
        }
      }
    }
  }
}

// ---------------- gemm256: 256x256 tile, 8 waves, BK=32, depth-2 counted pipeline ----------
// B read DIRECTLY as f32 from HBM (no conversion pass): LDS per buf = A 16KB fp16 +
// B 32KB f32; 3 bufs = 144KB. B chunk swizzle: slot = c ^ (row&7) over 8x16B chunks,
// inverse applied on the pre-swizzled per-lane global source. Fragments converted
// f32->fp16 at read time (8 ds_read_b128 + 32 cvt per wave-tile, hidden under MFMA).
// PAIR=1: B rows interleave two matrices (w1/w3 fusion) by addressing:
//   row r -> matrix (r>>4)&1, source row (r>>5)*16 + (r&15).
// MODE: 0 dense | 1 gather A rows via idx, expert by seg | 2 direct A, expert by seg.
// EPI: 4 fp16(+bias) | 5 fused swiglu -> fp16, Nh=N/2
template <int EPI, int MODE, int PAIR>
__global__ __launch_bounds__(512) void gemm256(
    const unsigned short* __restrict__ A, const float* __restrict__ B1,
    const float* __restrict__ B3, const float* __restrict__ bias,
    void* __restrict__ Cv, const int* __restrict__ idx, const int* __restrict__ seg,
    int M, int N, int K) {
  __shared__ __align__(16) char smem[147456];  // 3 bufs x 49152 B
  const int tid = threadIdx.x;
  const int lane = tid & 63;
  const int wv = tid >> 6;           // 0..7
  const int wr = wv >> 2;            // 0..1 (m half)
  const int wc = wv & 3;             // 0..3 (n quarter)
  const int fr = lane & 15, fc = lane >> 4;

  const int nwg = gridDim.x;
  const int bid = blockIdx.x;
  const int swzb = (bid & 7) * (nwg >> 3) + (bid >> 3);
  const int gm = M >> 8;
  const int m0 = (swzb % gm) * 256, n0 = (swzb / gm) * 256;
  if (MODE != 0 && m0 >= seg[4]) return;

  const float* B1p = B1;
  const float* B3p = B3;
  if constexpr (MODE != 0) {
    int e = 0;
#pragma unroll
    for (int i = 1; i < 4; ++i)
      if (m0 >= seg[i]) e = i;
    if constexpr (PAIR) {
      B1p = B1 + (size_t)e * (N >> 1) * K;
      B3p = B3 + (size_t)e * (N >> 1) * K;
    } else {
      B1p = B1 + (size_t)e * N * K;
    }
  }

  // ---- A staging (fp16, unchanged scheme): 2 gld16/wave/tile ----
  const int srowA = lane >> 2;                              // 0..15
  const int sccA = ((lane & 3) ^ ((lane >> 3) & 3)) << 3;   // shorts
  int mr0, mr1;
  if constexpr (MODE == 1) {
    mr0 = idx[m0 + wv * 16 + srowA];
    mr1 = idx[m0 + 128 + wv * 16 + srowA];
  } else {
    mr0 = m0 + wv * 16 + srowA;
    mr1 = m0 + 128 + wv * 16 + srowA;
  }
  const unsigned short* gA0 = A + (size_t)mr0 * K + sccA;
  const unsigned short* gA1 = A + (size_t)mr1 * K + sccA;

  // ---- B staging (f32): 4 gld16/wave/tile; rows [wv*32, +32) in 4 sweeps of 8 ----
  const int srowB = lane >> 3;                              // 0..7 (also = row&7)
  const int sccB = ((lane & 7) ^ srowB) << 2;               // floats (pre-swizzled chunk)
  const float* gB[4];
#pragma unroll
  for (int s = 0; s < 4; ++s) {
    const int rB = n0 + wv * 32 + s * 8 + srowB;
    const float* bsrc;
    if constexpr (PAIR) {
      const float* mptr = ((rB >> 4) & 1) ? B3p : B1p;
      bsrc = mptr + (size_t)((rB >> 5) * 16 + (rB & 15)) * K;
    } else {
      bsrc = B1p + (size_t)rB * K;
    }
    gB[s] = bsrc + sccB;
  }

  // fragment read geometry: A (shorts, row=32sh): mask (fr>>1)&3 over 4 chunks
  const int swA_ = (fr >> 1) & 3;
  const int foA = ((fc ^ swA_) << 3);
  const int aoff = (wr * 128 + fr) * 32 + foA;  // + mi*512
  // B (floats, row=32f): mask fr&7 over 8 chunks; frag = chunks {2fc, 2fc+1}
  const int mB = fr & 7;
  const int bc0 = ((2 * fc) ^ mB) << 2;         // float offset of low half
  const int bc1 = ((2 * fc + 1) ^ mB) << 2;     // float offset of high half

  f32x4 acc[8][4];
#pragma unroll
  for (int i = 0; i < 8; ++i) {
#pragma unroll
    for (int j = 0; j < 4; ++j) acc[i][j] = (f32x4)0.f;
  }

  auto STAGE_A = [&](int buf, int kt) {
    char* bb = smem + buf * 49152;
    gld16(gA0 + kt, bb + wv * 1024);
    gld16(gA1 + kt, bb + 8192 + wv * 1024);
  };
  auto STAGE_B = [&](int buf, int kt) {
    char* bb = smem + buf * 49152 + 16384 + wv * 4096;
#pragma unroll
    for (int s = 0; s < 4; ++s) gld16(gB[s] + kt, bb + s * 1024);
  };

  const int nk = K >> 5;
  // prologue: stage K-tiles 0 (buf0) and 1 (buf1): 12 loads outstanding
  STAGE_A(0, 0);
  STAGE_B(0, 0);
  STAGE_A(1, 32);
  STAGE_B(1, 32);

  int cur = 0;
  for (int t = 0; t < nk; ++t) {
    // tile t's 6 loads complete; tile t+1's 6 may remain in flight
    if (t < nk - 1)
      asm volatile("s_waitcnt vmcnt(6)" ::: "memory");
    else
      asm volatile("s_waitcnt vmcnt(0)" ::: "memory");
    __builtin_amdgcn_s_barrier();
    __builtin_amdgcn_sched_barrier(0);

    const unsigned short* sA = (const unsigned short*)(smem + cur * 49152);
    const float* sB = (const float*)(smem + cur * 49152 + 16384);
    int nxt = cur + 2;
    if (nxt >= 3) nxt -= 3;
    const bool more = (t + 2) < nk;
    const int kn = (t + 2) << 5;

    // ---- B frags: 8 ds_read_b128 f32 + convert to fp16 ----
    f16x8 bfr[4];
#pragma unroll
    for (int ni = 0; ni < 4; ++ni) {
      const float* rowp = sB + (wc * 64 + ni * 16 + fr) * 32;
      float4 x = *(const float4*)&rowp[bc0];
      float4 y = *(const float4*)&rowp[bc1];
      f16x8 b;
      b[0] = (_Float16)x.x; b[1] = (_Float16)x.y; b[2] = (_Float16)x.z; b[3] = (_Float16)x.w;
      b[4] = (_Float16)y.x; b[5] = (_Float16)y.y; b[6] = (_Float16)y.z; b[7] = (_Float16)y.w;
      bfr[ni] = b;
    }
    f16x8 b0 = bfr[0], b1 = bfr[1], b2 = bfr[2], b3 = bfr[3];

    // ---- phase 0: A frags 0,1; issue next-next A ----
    {
      f16x8 a0 = *(const f16x8*)&sA[aoff];
      f16x8 a1 = *(const f16x8*)&sA[aoff + 512];
      if (more) STAGE_A(nxt, kn);
      __builtin_amdgcn_sched_barrier(0);
      __builtin_amdgcn_s_setprio(1);
      acc[0][0] = MFMA16(a0, b0, acc[0][0]);
      acc[0][1] = MFMA16(a0, b1, acc[0][1]);
      acc[0][2] = MFMA16(a0, b2, acc[0][2]);
      acc[0][3] = MFMA16(a0, b3, acc[0][3]);
      acc[1][0] = MFMA16(a1, b0, acc[1][0]);
      acc[1][1] = MFMA16(a1, b1, acc[1][1]);
      acc[1][2] = MFMA16(a1, b2, acc[1][2]);
      acc[1][3] = MFMA16(a1, b3, acc[1][3]);
      __builtin_amdgcn_s_setprio(0);
      __builtin_amdgcn_sched_barrier(0);
    }
    // ---- phase 1: A frags 2,3; issue next-next B ----
    {
      f16x8 a0 = *(const f16x8*)&sA[aoff + 1024];
      f16x8 a1 = *(const f16x8*)&sA[aoff + 1536];
      if (more) STAGE_B(nxt, kn);
      __builtin_amdgcn_sched_barrier(0);
      __builtin_amdgcn_s_setprio(1);
      acc[2][0] = MFMA16(a0, b0, acc[2][0]);
      acc[2][1] = MFMA16(a0, b1, acc[2][1]);
      acc[2][2] = MFMA16(a0, b2, acc[2][2]);
      acc[2][3] = MFMA16(a0, b3, acc[2][3]);
      acc[3][0] = MFMA16(a1, b0, acc[3][0]);
      acc[3][1] = MFMA16(a1, b1, acc[3][1]);
      acc[3][2] = MFMA16(a1, b2, acc[3][2]);
      acc[3][3] = MFMA16(a1, b3, acc[3][3]);
      __builtin_amdgcn_s_setprio(0);
      __builtin_amdgcn_sched_barrier(0);
    }
    // ---- phase 2: A frags 4,5 ----
    {
      f16x8 a0 = *(const f16x8*)&sA[aoff + 2048];
      f16x8 a1 = *(const f16x8*)&sA[aoff + 2560];
      __builtin_amdgcn_sched_barrier(0);
      __builtin_amdgcn_s_setprio(1);
      acc[4][0] = MFMA16(a0, b0, acc[4][0]);
      acc[4][1] = MFMA16(a0, b1, acc[4][1]);
      acc[4][2] = MFMA16(a0, b2, acc[4][2]);
      acc[4][3] = MFMA16(a0, b3, acc[4][3]);
      acc[5][0] = MFMA16(a1, b0, acc[5][0]);
      acc[5][1] = MFMA16(a1, b1, acc[5][1]);
      acc[5][2] = MFMA16(a1, b2, acc[5][2]);
      acc[5][3] = MFMA16(a1, b3, acc[5][3]);
      __builtin_amdgcn_s_setprio(0);
      __builtin_amdgcn_sched_barrier(0);
    }
    // ---- phase 3: A frags 6,7 ----
    {
      f16x8 a0 = *(const f16x8*)&sA[aoff + 3072];
      f16x8 a1 = *(const f16x8*)&sA[aoff + 3584];
      __builtin_amdgcn_sched_barrier(0);
      __builtin_amdgcn_s_setprio(1);
      acc[6][0] = MFMA16(a0, b0, acc[6][0]);
      acc[6][1] = MFMA16(a0, b1, acc[6][1]);
      acc[6][2] = MFMA16(a0, b2, acc[6][2]);
      acc[6][3] = MFMA16(a0, b3, acc[6][3]);
      acc[7][0] = MFMA16(a1, b0, acc[7][0]);
      acc[7][1] = MFMA16(a1, b1, acc[7][1]);
      acc[7][2] = MFMA16(a1, b2, acc[7][2]);
      acc[7][3] = MFMA16(a1, b3, acc[7][3]);
      __builtin_amdgcn_s_setprio(0);
      __builtin_amdgcn_sched_barrier(0);
    }
    cur += 1;
    if (cur >= 3) cur -= 3;
  }

  // epilogue; frag: D[row=fc*4+i][col=fr]
  if constexpr (EPI == 5) {
    unsigned short* Ch = (unsigned short*)Cv;
    const int Nh = N >> 1;
#pragma unroll
    for (int mi = 0; mi < 8; ++mi) {
#pragma unroll
      for (int p = 0; p < 2; ++p) {
        const int hcol = (((n0 + wc * 64) >> 5) + p) * 16 + fr;
        const int mb = m0 + wr * 128 + mi * 16 + fc * 4;
#pragma unroll
        for (int i = 0; i < 4; ++i) {
          const int m = mb + i;
          float v1 = acc[mi][2 * p][i];
          float v3 = acc[mi][2 * p + 1][i];
          float y = v1 / (1.f + __expf(-v1)) * v3;
          Ch[(size_t)m * Nh + hcol] = f2h(y);
        }
      }
    }
  } else {
    unsigned short* Ch = (unsigned short*)Cv;
#pragma unroll
    for (int mi = 0; mi < 8; ++mi) {
#pragma unroll
      for (int ni = 0; ni < 4; ++ni) {
        const int n = n0 + wc * 64 + ni * 16 + fr;
        const int mb = m0 + wr * 128 + mi * 16 + fc * 4;
#pragma unroll
        for (int i = 0; i < 4; ++i) {
          const int m = mb + i;
          float v = acc[mi][ni][i];
          if (bias) v += bias[n];
          Ch[(size_t)m * N + n] = f2h(v);
        }
      }
    }
  }
}

// ---------------- host ----------------

extern "C" void kernel_launch(void* const* d_in, const int* in_sizes, int n_in,
                              void* d_out, int out_size, void* d_ws, size_t ws_size,
                              hipStream_t stream) {
  (void)in_sizes; (void)n_in; (void)out_size; (void)ws_size;
  const float* hs = (const float*)d_in[0];
  const float* temb = (const float*)d_in[1];
  const float* rope = (const float*)d_in[2];
  const float* adaw = (const float*)d_in[3];
  const float* adab = (const float*)d_in[4];
  const float* qkvw = (const float*)d_in[5];
  const float* qkvb = (const float*)d_in[6];
  const float* qnw = (const float*)d_in[7];
  const float* knw = (const float*)d_in[8];
  const float* outw = (const float*)d_in[9];
  const float* outb = (const float*)d_in[10];
  const float* gatew = (const float*)d_in[11];
  const float* ew1 = (const float*)d_in[12];
  const float* ew2 = (const float*)d_in[13];
  const float* ew3 = (const float*)d_in[14];
  const float* sw1 = (const float*)d_in[15];
  const float* sw2 = (const float*)d_in[16];
  const float* sw3 = (const float*)d_in[17];
  float* out = (float*)d_out;
  char* ws = (char*)d_ws;

  size_t off = 0;
  auto give = [&](size_t nbytes) {
    size_t r = off;
    off += (nbytes + 255) & ~(size_t)255;
    return r;
  };
  const size_t T = T_TOK, D = DIM;
  size_t o_mod = give(15360 * 4);
  size_t o_ss = give(D * 4);
  size_t o_wd = give(T * 4 * 4);
  size_t o_idx = give(MPAD * 4);
  size_t o_seg = give(8 * 4);
  size_t o_slot = give(T * 2 * 4);
  size_t o_wab = give(T * 2 * 4);
  size_t o_nh = give(T * D * 2);      // nh fp16; later nh2
  size_t o_qkvh = give(T * 7680 * 2); // qkv fp16; region later reused as hmid
  size_t o_qh = give(T * D * 2);
  size_t o_kh = give(T * D * 2);
  size_t o_vt = give(T * D * 2);
  size_t o_obf = give(T * D * 2);
  size_t o_h2 = give(T * D * 4);
  size_t o_yc = give((size_t)MPAD * D * 2);       // compact expert outputs fp16
  size_t o_hmid2 = give(T * SHID_E * 2);          // shared-expert mid
  // fp16 weights (only the two gemm128 B's still need conversion)
  size_t o_outw = give((size_t)2560 * 2560 * 2);
  size_t o_sw2 = give((size_t)2560 * SHID_E * 2);

  float* mod = (float*)(ws + o_mod);
  float* ss = (float*)(ws + o_ss);
  float* wd = (float*)(ws + o_wd);
  int* idxb = (int*)(ws + o_idx);
  int* segp = (int*)(ws + o_seg);
  int* slotAB = (int*)(ws + o_slot);
  float* wAB = (float*)(ws + o_wab);
  unsigned short* nh_h = (unsigned short*)(ws + o_nh);
  unsigned short* qkvh = (unsigned short*)(ws + o_qkvh);
  unsigned short* qh = (unsigned short*)(ws + o_qh);
  unsigned short* kh = (unsigned short*)(ws + o_kh);
  unsigned short* vt = (unsigned short*)(ws + o_vt);
  unsigned short* obf = (unsigned short*)(ws + o_obf);
  float* h2 = (float*)(ws + o_h2);
  unsigned short* yc = (unsigned short*)(ws + o_yc);
  unsigned short* hmid2 = (unsigned short*)(ws + o_hmid2);
  unsigned short* outw_h = (unsigned short*)(ws + o_outw);
  unsigned short* sw2_h = (unsigned short*)(ws + o_sw2);
  unsigned short* nh2 = nh_h;
  // hmid (MPAD x 6912 fp16 = 70.8 MB) aliases qkvh..obf (73.4 MB), dead after out-proj
  unsigned short* hmid = qkvh;

  // 0) small weight conversion (outw + sw2 only; all gemm256 B's read f32 directly)
  cvt_all2<<<2048, 256, 0, stream>>>(outw, outw_h, 2560L * 2560 / 8,
                                     sw2, sw2_h, 2560L * SHID_E / 8);
  // 1) adaLN modulation
  silu_k<<<10, 256, 0, stream>>>(temb, ss);
  adaln_gemv<<<3840, 256, 0, stream>>>(ss, adaw, adab, mod);
  // 2) LN1 + modulate (fp16)
  ln_mod<<<T, 256, 0, stream>>>(hs, mod, mod + D, nh_h);
  // 3) qkv GEMM -> fp16 (256-tile, f32 B direct)
  gemm256<4, 0, 0><<<240, 512, 0, stream>>>(nh_h, qkvw, nullptr, qkvb, qkvh,
                                            nullptr, nullptr, 2048, 7680, 2560);
  // 4) RMSNorm + RoPE
  rmsrope<<<T, 256, 0, stream>>>(qkvh, qnw, knw, rope, qh, kh);
  // 5) V transpose
  transpose_v<<<dim3(80, 64), dim3(32, 8), 0, stream>>>(qkvh, vt);
  // 6) MFMA flash attention
  fattn<<<dim3(32, 20), 256, 0, stream>>>(qh, kh, vt, obf);
  // 7) out proj + gate_msa residual -> h2 f32
  gemm128<1, 0><<<16 * 20, 256, 0, stream>>>(obf, outw_h, outb, h2,
                                             mod + 2 * D, hs, nullptr, nullptr,
                                             nullptr, nullptr, nullptr, 2048, 2560, 2560);
  // 8) LN2 + modulate + routing, then concatenated 256-padded compaction
  ln2_route<<<T, 256, 0, stream>>>(h2, mod + 3 * D, mod + 4 * D, gatew, nh2, wd);
  route_compact<<<1, 256, 0, stream>>>(wd, idxb, segp, slotAB, wAB);
  // 9) MoE experts: fused w1w3+swiglu (PAIR addressing, f32 B) + w2 (f32 B)
  gemm256<5, 1, 1><<<20 * 54, 512, 0, stream>>>(nh2, ew1, ew3, nullptr, hmid,
                                                idxb, segp, MPAD, 2 * HID_E, 2560);
  gemm256<4, 2, 0><<<20 * 10, 512, 0, stream>>>(hmid, ew2, nullptr, nullptr, yc,
                                                nullptr, segp, MPAD, 2560, 6912);
  // 10) shared expert (PAIR, f32 B) + final combine w/ yc gather
  gemm256<5, 0, 1><<<8 * 28, 512, 0, stream>>>(nh2, sw1, sw3, nullptr, hmid2,
                                               nullptr, nullptr, 2048, 2 * SHID_E, 2560);
  gemm128<6, 0><<<16 * 20, 256, 0, stream>>>(hmid2, sw2_h, nullptr, out,
                                             mod + 5 * D, h2, nullptr, nullptr,
                                             slotAB, wAB, yc, 2048, 2560, 3584);
}